// Round 8
// baseline (214.671 us; speedup 1.0000x reference)
//
#include <hip/hip_runtime.h>
#include <hip/hip_bf16.h>
#include <cstdint>
#include <cstddef>

// B=8192, CIN=16, 6x6->5x5 (k=2 VALID), FM=64, DK=DV=NH=32 (dkh=1), HID=128, OUT=5.
// R8 = R7 minus the prep dispatch (absorbed into k1), qs stride 28, 12/13 i-split.
// act layout [b][pos][ch] (dense K-permuted); w1bp pre-permuted to match.

typedef __attribute__((ext_vector_type(4))) float f32x4;
typedef __attribute__((ext_vector_type(8))) __bf16 bf16x8;
typedef __attribute__((ext_vector_type(4))) __bf16 bf16x4;

#define LOG2E 1.4426950408889634f

// raw v_exp_f32 (2^x) — exp2f() lowers to the OCML wrapper (~4 extra VALU ops),
// measured as the R4->R6 attention regression (R7 confirmed the fix).
__device__ __forceinline__ float fast_exp2(float x) {
#if __has_builtin(__builtin_amdgcn_exp2f)
  return __builtin_amdgcn_exp2f(x);
#else
  return __expf(x * 0.6931471805599453f);
#endif
}

// v_mfma_f32_16x16x32_bf16 (bench-verified layout R2-R7):
// A: lane holds A[m=lane&15][k=quad*8+j]; B: W[n=lane&15][k=quad*8+j];
// C/D: col=lane&15, row=quad*4+reg.
__device__ __forceinline__ f32x4 mfma16(bf16x8 a, bf16x8 b, f32x4 c) {
  return __builtin_amdgcn_mfma_f32_16x16x32_bf16(a, b, c, 0, 0, 0);
}

// ---------------- k1: fused conv+qkv GEMM + attention + 1x1 conv (+ absorbed prep) ----------------
// 2048 blocks x 256 thr (4 waves); block = 4 batches -> GEMM M=100 (7 m-tiles).
// LDS: region A (6400 B) = xs (phase1: x bf16, 4*576) / as_ (phase2/3: [row][head], 100*32)
//      region B (21504 B) = qs [bl][ch 0..95][pos stride 28] (56 B rows; k ch pre-scaled log2e)
__global__ __launch_bounds__(256) void k1(
    const float* __restrict__ x,
    const float* __restrict__ conv_w, const float* __restrict__ conv_b,
    const float* __restrict__ qkv_w,  const float* __restrict__ qkv_b,
    const float* __restrict__ attn_w, const float* __restrict__ attn_b,
    const float* __restrict__ w1, const float* __restrict__ w2,
    __hip_bfloat16* __restrict__ act,
    __hip_bfloat16* __restrict__ w1bp, __hip_bfloat16* __restrict__ w2b) {
  const int t = threadIdx.x;
  const int lane = t & 63, wave = t >> 6;
  const int l15 = lane & 15, quad = lane >> 4;
  const int b0 = blockIdx.x * 4;

  __shared__ __align__(16) char lds_raw[6400 + 21504];
  __bf16* xs  = (__bf16*)lds_raw;          // phase 1 (2304 elems)
  __bf16* as_ = (__bf16*)lds_raw;          // phase 2/3 (3200 elems, stride 32)
  __bf16* qs  = (__bf16*)(lds_raw + 6400); // q:0-31 k:32-63(x log2e) v:64-95, stride 28

  // ---- absorbed prep for k2 (read/write locality fixed vs R5: one w1 row per
  //      block, L1-window reads, contiguous bf16 writes). No intra-kernel reader.
  if (blockIdx.x < 128) {
    const int n = blockIdx.x;
    const float* wr = w1 + n * 1600;
    __hip_bfloat16* wo = w1bp + n * 1600;
    for (int o = t; o < 1600; o += 256) {
      int c = o & 63, p = o >> 6;
      wo[o] = __float2bfloat16(wr[c * 25 + p]);
    }
  } else if (blockIdx.x < 160) {
    int i = (blockIdx.x - 128) * 256 + t;
    w2b[i] = __float2bfloat16(w2[i]);
  }

  // ---- stage x -> bf16 LDS ----
  const float* xb = x + (size_t)b0 * 576;
#pragma unroll
  for (int i = 0; i < 9; ++i) {
    int f = t + i * 256;
    xs[f] = __float2bfloat16(xb[f]);
  }

  // ---- B-frags direct from fp32 weights (L2-hot 8 KB; replaces wqb) + biases ----
  bf16x8 bfr[8][2];
  float bias[8];
#pragma unroll
  for (int nt = 0; nt < 8; ++nt) {
    int ch = nt * 16 + l15;
    const float* wrow = (ch < 32) ? (conv_w + ch * 64) : (qkv_w + (ch - 32) * 64);
    bias[nt] = (ch < 32) ? conv_b[ch] : qkv_b[ch - 32];
#pragma unroll
    for (int ks = 0; ks < 2; ++ks) {
      float4 a = *(const float4*)(wrow + ks * 32 + quad * 8);
      float4 b = *(const float4*)(wrow + ks * 32 + quad * 8 + 4);
      bf16x8 f;
      f[0] = (__bf16)__float2bfloat16(a.x); f[1] = (__bf16)__float2bfloat16(a.y);
      f[2] = (__bf16)__float2bfloat16(a.z); f[3] = (__bf16)__float2bfloat16(a.w);
      f[4] = (__bf16)__float2bfloat16(b.x); f[5] = (__bf16)__float2bfloat16(b.y);
      f[6] = (__bf16)__float2bfloat16(b.z); f[7] = (__bf16)__float2bfloat16(b.w);
      bfr[nt][ks] = f;
    }
  }
  __syncthreads();

  // ---- phase 1: implicit GEMM, M=100, N=128, K=64 ----
  for (int mt = wave; mt < 7; mt += 4) {
    int row = mt * 16 + l15;
    int rc = row < 99 ? row : 99;
    int bl = rc / 25, pos = rc - bl * 25;
    int ii = pos / 5, jj = pos - ii * 5;
    const __bf16* xp = xs + bl * 576 + ii * 6 + jj;
    bf16x8 af[2];
#pragma unroll
    for (int ks = 0; ks < 2; ++ks) {
      const __bf16* p0 = xp + (ks * 8 + quad * 2) * 36;
      bf16x8 a;
      a[0] = p0[0];  a[1] = p0[1];  a[2] = p0[6];  a[3] = p0[7];
      a[4] = p0[36]; a[5] = p0[37]; a[6] = p0[42]; a[7] = p0[43];
      af[ks] = a;
    }
    f32x4 acc[8];
#pragma unroll
    for (int nt = 0; nt < 8; ++nt) acc[nt] = (f32x4){0.f, 0.f, 0.f, 0.f};
#pragma unroll
    for (int ks = 0; ks < 2; ++ks)
#pragma unroll
      for (int nt = 0; nt < 8; ++nt)
        acc[nt] = mfma16(af[ks], bfr[nt][ks], acc[nt]);

#pragma unroll
    for (int r = 0; r < 4; ++r) {
      int orow = mt * 16 + quad * 4 + r;
      if (orow < 100) {
        int ob = orow / 25, op = orow - ob * 25;
#pragma unroll
        for (int nt = 0; nt < 8; ++nt) {
          float v = acc[nt][r] + bias[nt];
          if (nt < 2) {  // conv_out ch 0..31 -> global with relu
            act[((size_t)(b0 + ob) * 25 + op) * 64 + nt * 16 + l15] =
                __float2bfloat16(fmaxf(v, 0.f));
          } else {       // qkv ch 0..95 -> LDS; k-channels (nt 4,5) pre-scaled by log2e
            if (nt == 4 || nt == 5) v *= LOG2E;
            qs[(ob * 96 + (nt - 2) * 16 + l15) * 28 + op] = __float2bfloat16(v);
          }
        }
      }
    }
  }
  __syncthreads();

  // ---- phase 2: attention, dkh=1; softmax without max-sub (|q.k| << fp32 exp range),
  //      e = 2^(q * k*log2e) via raw v_exp_f32; 5 independent acc chains.
  //      waves 0,1: i 0..11; waves 2,3: i 12..24 (wave-uniform bounds, no dup).
  {
    const int pair = t & 127, half = t >> 7;
    const int bl = pair >> 5, n = pair & 31;
    const __bf16* qp = qs + (bl * 96 + n) * 28;
    const __bf16* kp = qp + 32 * 28;
    const __bf16* vp = qp + 64 * 28;
    float kl[25], vv[25];
#pragma unroll
    for (int c4 = 0; c4 < 6; ++c4) {
      bf16x4 b = *(const bf16x4*)(kp + c4 * 4);
      bf16x4 c = *(const bf16x4*)(vp + c4 * 4);
#pragma unroll
      for (int z = 0; z < 4; ++z) {
        kl[c4 * 4 + z] = (float)b[z];
        vv[c4 * 4 + z] = (float)c[z];
      }
    }
    kl[24] = (float)kp[24]; vv[24] = (float)vp[24];

    const int i0 = half * 12;
    float qv[13];
    {
      const __bf16* qbase = qp + i0;  // 8B-aligned for i0 in {0,12}
      bf16x4 q0 = *(const bf16x4*)(qbase);
      bf16x4 q1 = *(const bf16x4*)(qbase + 4);
      bf16x4 q2 = *(const bf16x4*)(qbase + 8);
#pragma unroll
      for (int z = 0; z < 4; ++z) {
        qv[z] = (float)q0[z]; qv[4 + z] = (float)q1[z]; qv[8 + z] = (float)q2[z];
      }
      qv[12] = (float)qbase[12];
    }

    auto do_i = [&](int z) {
      const float qi = qv[z];
      float s0 = 0.f, s1 = 0.f, s2 = 0.f, s3 = 0.f, s4 = 0.f;
      float o0 = 0.f, o1 = 0.f, o2 = 0.f, o3 = 0.f, o4 = 0.f;
#pragma unroll
      for (int g = 0; g < 5; ++g) {
        float e0 = fast_exp2(qi * kl[g * 5 + 0]);
        float e1 = fast_exp2(qi * kl[g * 5 + 1]);
        float e2 = fast_exp2(qi * kl[g * 5 + 2]);
        float e3 = fast_exp2(qi * kl[g * 5 + 3]);
        float e4 = fast_exp2(qi * kl[g * 5 + 4]);
        s0 += e0; o0 = __builtin_fmaf(e0, vv[g * 5 + 0], o0);
        s1 += e1; o1 = __builtin_fmaf(e1, vv[g * 5 + 1], o1);
        s2 += e2; o2 = __builtin_fmaf(e2, vv[g * 5 + 2], o2);
        s3 += e3; o3 = __builtin_fmaf(e3, vv[g * 5 + 3], o3);
        s4 += e4; o4 = __builtin_fmaf(e4, vv[g * 5 + 4], o4);
      }
      float ss = ((s0 + s1) + (s2 + s3)) + s4;
      float oo = ((o0 + o1) + (o2 + o3)) + o4;
      as_[(bl * 25 + i0 + z) * 32 + n] = __float2bfloat16(oo * __builtin_amdgcn_rcpf(ss));
    };
    if (half) {
#pragma unroll
      for (int z = 0; z < 13; ++z) do_i(z);
    } else {
#pragma unroll
      for (int z = 0; z < 12; ++z) do_i(z);
    }
  }
  __syncthreads();

  // ---- phase 3: 1x1 conv via MFMA. M=100 rows, K=32 heads, N=32 ----
  {
    bf16x8 bw[2]; float ab[2];
#pragma unroll
    for (int nt2 = 0; nt2 < 2; ++nt2) {
      int n = nt2 * 16 + l15;
#pragma unroll
      for (int j = 0; j < 8; ++j)
        bw[nt2][j] = (__bf16)__float2bfloat16(attn_w[n * 32 + quad * 8 + j]);
      ab[nt2] = attn_b[n];
    }
    for (int mt = wave; mt < 7; mt += 4) {
      int row = mt * 16 + l15;
      int rc = row < 99 ? row : 99;
      bf16x8 af = *(const bf16x8*)(as_ + rc * 32 + quad * 8);
      f32x4 acc[2];
#pragma unroll
      for (int nt2 = 0; nt2 < 2; ++nt2)
        acc[nt2] = mfma16(af, bw[nt2], (f32x4){0.f, 0.f, 0.f, 0.f});
#pragma unroll
      for (int r = 0; r < 4; ++r) {
        int orow = mt * 16 + quad * 4 + r;
        if (orow < 100) {
          int ob = orow / 25, op = orow - ob * 25;
#pragma unroll
          for (int nt2 = 0; nt2 < 2; ++nt2)
            act[((size_t)(b0 + ob) * 25 + op) * 64 + 32 + nt2 * 16 + l15] =
                __float2bfloat16(fmaxf(acc[nt2][r] + ab[nt2], 0.f));
        }
      }
    }
  }
}

// ---------------- k2: fused dense chain — R2-proven 32-row/2-acc shape ----------------
// 256 blocks x 512 thr (8 waves = 2 wm x 4 wn); block = 32 rows.
__global__ __launch_bounds__(512) void k2(
    const __hip_bfloat16* __restrict__ act,
    const __hip_bfloat16* __restrict__ w1bp, const float* __restrict__ b1,
    const __hip_bfloat16* __restrict__ w2b, const float* __restrict__ b2,
    const float* __restrict__ w3, const float* __restrict__ b3,
    float* __restrict__ out) {
  const int t = threadIdx.x;
  const int lane = t & 63;
  const int wave = t >> 6;   // 0..7
  const int wm = wave >> 2;  // 0..1
  const int wn = wave & 3;   // 0..3
  const int l15 = lane & 15;
  const int quad = lane >> 4;  // 0..3
  const int b0 = blockIdx.x * 32;

  __shared__ __hip_bfloat16 C1s[32 * 136];
  __shared__ __hip_bfloat16 C2s[32 * 72];

  // ---- layer 1: [32,1600] x [128,1600]^T ----
  f32x4 acc0 = {0.f, 0.f, 0.f, 0.f};
  f32x4 acc1 = {0.f, 0.f, 0.f, 0.f};
  const __bf16* aptr  = (const __bf16*)act + (size_t)(b0 + wm * 16 + l15) * 1600 + quad * 8;
  const __bf16* bptr0 = (const __bf16*)w1bp + (size_t)(wn * 32 + l15) * 1600 + quad * 8;
  const __bf16* bptr1 = bptr0 + 16 * 1600;
#pragma unroll 5
  for (int k0 = 0; k0 < 1600; k0 += 32) {
    bf16x8 av  = *(const bf16x8*)(aptr + k0);
    bf16x8 bv0 = *(const bf16x8*)(bptr0 + k0);
    bf16x8 bv1 = *(const bf16x8*)(bptr1 + k0);
    acc0 = mfma16(av, bv0, acc0);
    acc1 = mfma16(av, bv1, acc1);
  }
  {
    const int col0 = wn * 32 + l15;
    const float bias0 = b1[col0];
    const float bias1 = b1[col0 + 16];
#pragma unroll
    for (int r = 0; r < 4; ++r) {
      const int row = wm * 16 + quad * 4 + r;
      C1s[row * 136 + col0]      = __float2bfloat16(fmaxf(acc0[r] + bias0, 0.f));
      C1s[row * 136 + col0 + 16] = __float2bfloat16(fmaxf(acc1[r] + bias1, 0.f));
    }
  }
  __syncthreads();

  // ---- layer 2: [32,128] x [64,128]^T ----
  f32x4 acc2 = {0.f, 0.f, 0.f, 0.f};
  {
    const __bf16* aL = (const __bf16*)C1s + (wm * 16 + l15) * 136 + quad * 8;
    const __bf16* bL = (const __bf16*)w2b + (wn * 16 + l15) * 128 + quad * 8;
#pragma unroll
    for (int k0 = 0; k0 < 128; k0 += 32)
      acc2 = mfma16(*(const bf16x8*)(aL + k0), *(const bf16x8*)(bL + k0), acc2);
  }
  {
    const int col = wn * 16 + l15;
    const float bias = b2[col];
#pragma unroll
    for (int r = 0; r < 4; ++r) {
      const int row = wm * 16 + quad * 4 + r;
      C2s[row * 72 + col] = __float2bfloat16(fmaxf(acc2[r] + bias, 0.f));
    }
  }
  __syncthreads();

  // ---- layer 3 (scalar, 160 outputs) ----
  if (t < 160) {
    const int row = t / 5;
    const int oc = t - row * 5;
    float s = b3[oc];
#pragma unroll
    for (int k = 0; k < 64; ++k)
      s += __bfloat162float(C2s[row * 72 + k]) * w3[oc * 64 + k];
    out[(size_t)(b0 + row) * 5 + oc] = s;
  }
}

extern "C" void kernel_launch(void* const* d_in, const int* in_sizes, int n_in,
                              void* d_out, int out_size, void* d_ws, size_t ws_size,
                              hipStream_t stream) {
  const float* x      = (const float*)d_in[0];
  const float* conv_w = (const float*)d_in[1];
  const float* conv_b = (const float*)d_in[2];
  const float* qkv_w  = (const float*)d_in[3];
  const float* qkv_b  = (const float*)d_in[4];
  const float* attn_w = (const float*)d_in[5];
  const float* attn_b = (const float*)d_in[6];
  const float* w1 = (const float*)d_in[7];
  const float* b1 = (const float*)d_in[8];
  const float* w2 = (const float*)d_in[9];
  const float* b2 = (const float*)d_in[10];
  const float* w3 = (const float*)d_in[11];
  const float* b3 = (const float*)d_in[12];
  float* out = (float*)d_out;

  // workspace layout (16B-aligned):
  //   act  [8192][25][64] bf16 : 26,214,400 B
  //   w1bp [128][1600]    bf16 :    409,600 B   (written by k1 blocks 0..127)
  //   w2b  [64][128]      bf16 :     16,384 B   (written by k1 blocks 128..159)
  char* ws = (char*)d_ws;
  __hip_bfloat16* act  = (__hip_bfloat16*)ws;
  __hip_bfloat16* w1bp = (__hip_bfloat16*)(ws + 26214400);
  __hip_bfloat16* w2b  = (__hip_bfloat16*)(ws + 26624000);

  k1<<<dim3(2048), dim3(256), 0, stream>>>(x, conv_w, conv_b, qkv_w, qkv_b,
                                           attn_w, attn_b, w1, w2, act, w1bp, w2b);
  k2<<<dim3(256), dim3(512), 0, stream>>>(act, w1bp, b1, w2b, b2, w3, b3, out);
}

// Round 9
// 178.211 us; speedup vs baseline: 1.2046x; 1.2046x over previous
//
#include <hip/hip_runtime.h>
#include <hip/hip_bf16.h>
#include <cstdint>
#include <cstddef>

// B=8192, CIN=16, 6x6->5x5 (k=2 VALID), FM=64, DK=DV=NH=32 (dkh=1), HID=128, OUT=5.
// R9 = R7 (best: k1=60us, VGPR 88) + qs stride 28 (5 blocks/CU) + log2e pre-scaled
// k-weights/bias in prep (uniform epilogue). NOTHING else touched (R5/R8 lesson:
// prologue register pressure is poison).
// act layout [b][pos][ch] (dense K-permuted); w1bp pre-permuted to match.

typedef __attribute__((ext_vector_type(4))) float f32x4;
typedef __attribute__((ext_vector_type(8))) __bf16 bf16x8;
typedef __attribute__((ext_vector_type(4))) __bf16 bf16x4;

#define LOG2E 1.4426950408889634f

// raw v_exp_f32 (2^x) — exp2f() lowers to the OCML wrapper (~4 extra VALU ops),
// measured as the R4->R6 attention regression (R7 confirmed the fix: -20us).
__device__ __forceinline__ float fast_exp2(float x) {
#if __has_builtin(__builtin_amdgcn_exp2f)
  return __builtin_amdgcn_exp2f(x);
#else
  return __expf(x * 0.6931471805599453f);
#endif
}

// v_mfma_f32_16x16x32_bf16 (bench-verified layout R2-R8):
// A: lane holds A[m=lane&15][k=quad*8+j]; B: W[n=lane&15][k=quad*8+j];
// C/D: col=lane&15, row=quad*4+reg.
__device__ __forceinline__ f32x4 mfma16(bf16x8 a, bf16x8 b, f32x4 c) {
  return __builtin_amdgcn_mfma_f32_16x16x32_bf16(a, b, c, 0, 0, 0);
}

// ---------------- prep: weight casts / permutes ----------------
// wqb rows 64..95 (k channels) and biasb[64..95] pre-scaled by LOG2E so k1's
// epilogue is branch/select-free and phase 2 can use raw exp2.
__global__ __launch_bounds__(256) void prep(
    const float* __restrict__ conv_w, const float* __restrict__ conv_b,
    const float* __restrict__ qkv_w,  const float* __restrict__ qkv_b,
    const float* __restrict__ w1, const float* __restrict__ w2,
    __hip_bfloat16* __restrict__ wqb, __hip_bfloat16* __restrict__ w1bp,
    __hip_bfloat16* __restrict__ w2b, float* __restrict__ biasb) {
  int i = blockIdx.x * 256 + threadIdx.x;
  if (i < 128 * 1600) {
    int n = i / 1600, r = i - n * 1600;
    int c = r & 63, p = r >> 6;
    w1bp[i] = __float2bfloat16(w1[n * 1600 + c * 25 + p]);
  }
  if (i < 8192) {
    float w = (i < 2048) ? conv_w[i] : qkv_w[i - 2048];
    if (i >= 4096 && i < 6144) w *= LOG2E;  // k-channel rows 64..95
    wqb[i] = __float2bfloat16(w);
    w2b[i] = __float2bfloat16(w2[i]);
  }
  if (i < 128) {
    float b = (i < 32) ? conv_b[i] : qkv_b[i - 32];
    if (i >= 64 && i < 96) b *= LOG2E;
    biasb[i] = b;
  }
}

// ---------------- k1: fused conv+qkv GEMM + attention + 1x1 conv ----------------
// 2048 blocks x 256 thr (4 waves); block = 4 batches -> GEMM M=100 (7 m-tiles).
// LDS: region A (6400 B) = xs (phase1: x bf16, 4*576) / as_ (phase2/3: [row][head], 100*32)
//      region B (21504 B) = qs [bl][ch 0..95][pos stride 28] (56 B rows; k pre-scaled log2e)
__global__ __launch_bounds__(256) void k1(
    const float* __restrict__ x,
    const float* __restrict__ biasb,
    const __hip_bfloat16* __restrict__ wqb,
    const float* __restrict__ attn_w, const float* __restrict__ attn_b,
    __hip_bfloat16* __restrict__ act) {
  const int t = threadIdx.x;
  const int lane = t & 63, wave = t >> 6;
  const int l15 = lane & 15, quad = lane >> 4;
  const int b0 = blockIdx.x * 4;

  __shared__ __align__(16) char lds_raw[6400 + 21504];
  __bf16* xs  = (__bf16*)lds_raw;          // phase 1 (2304 elems)
  __bf16* as_ = (__bf16*)lds_raw;          // phase 2/3 (3200 elems, stride 32)
  __bf16* qs  = (__bf16*)(lds_raw + 6400); // q:0-31 k:32-63(x log2e) v:64-95, stride 28

  // ---- stage x -> bf16 LDS ----
  const float* xb = x + (size_t)b0 * 576;
#pragma unroll
  for (int i = 0; i < 9; ++i) {
    int f = t + i * 256;
    xs[f] = __float2bfloat16(xb[f]);
  }

  // ---- B-frags from bf16 wqb + pre-scaled biases ----
  bf16x8 bfr[8][2];
#pragma unroll
  for (int nt = 0; nt < 8; ++nt)
#pragma unroll
    for (int ks = 0; ks < 2; ++ks)
      bfr[nt][ks] = *(const bf16x8*)((const __bf16*)wqb + (nt * 16 + l15) * 64 + ks * 32 + quad * 8);
  float bias[8];
#pragma unroll
  for (int nt = 0; nt < 8; ++nt) bias[nt] = biasb[nt * 16 + l15];
  __syncthreads();

  // ---- phase 1: implicit GEMM, M=100, N=128, K=64 ----
  for (int mt = wave; mt < 7; mt += 4) {
    int row = mt * 16 + l15;
    int rc = row < 99 ? row : 99;
    int bl = rc / 25, pos = rc - bl * 25;
    int ii = pos / 5, jj = pos - ii * 5;
    const __bf16* xp = xs + bl * 576 + ii * 6 + jj;
    bf16x8 af[2];
#pragma unroll
    for (int ks = 0; ks < 2; ++ks) {
      const __bf16* p0 = xp + (ks * 8 + quad * 2) * 36;
      bf16x8 a;
      a[0] = p0[0];  a[1] = p0[1];  a[2] = p0[6];  a[3] = p0[7];
      a[4] = p0[36]; a[5] = p0[37]; a[6] = p0[42]; a[7] = p0[43];
      af[ks] = a;
    }
    f32x4 acc[8];
#pragma unroll
    for (int nt = 0; nt < 8; ++nt) acc[nt] = (f32x4){0.f, 0.f, 0.f, 0.f};
#pragma unroll
    for (int ks = 0; ks < 2; ++ks)
#pragma unroll
      for (int nt = 0; nt < 8; ++nt)
        acc[nt] = mfma16(af[ks], bfr[nt][ks], acc[nt]);

#pragma unroll
    for (int r = 0; r < 4; ++r) {
      int orow = mt * 16 + quad * 4 + r;
      if (orow < 100) {
        int ob = orow / 25, op = orow - ob * 25;
#pragma unroll
        for (int nt = 0; nt < 8; ++nt) {
          float v = acc[nt][r] + bias[nt];
          if (nt < 2) {  // conv_out ch 0..31 -> global with relu
            act[((size_t)(b0 + ob) * 25 + op) * 64 + nt * 16 + l15] =
                __float2bfloat16(fmaxf(v, 0.f));
          } else {       // qkv ch 0..95 -> LDS (k already log2e-scaled via weights)
            qs[(ob * 96 + (nt - 2) * 16 + l15) * 28 + op] = __float2bfloat16(v);
          }
        }
      }
    }
  }
  __syncthreads();

  // ---- phase 2: attention, dkh=1; softmax without max-sub (|q.k| << fp32 exp range),
  //      e = 2^(q * k*log2e) via raw v_exp_f32; 5 independent acc chains.
  {
    const int pair = t & 127, half = t >> 7;
    const int bl = pair >> 5, n = pair & 31;
    const __bf16* qp = qs + (bl * 96 + n) * 28;
    const __bf16* kp = qp + 32 * 28;
    const __bf16* vp = qp + 64 * 28;
    float kl[25], vv[25];
#pragma unroll
    for (int c4 = 0; c4 < 6; ++c4) {
      bf16x4 b = *(const bf16x4*)(kp + c4 * 4);
      bf16x4 c = *(const bf16x4*)(vp + c4 * 4);
#pragma unroll
      for (int z = 0; z < 4; ++z) {
        kl[c4 * 4 + z] = (float)b[z];
        vv[c4 * 4 + z] = (float)c[z];
      }
    }
    kl[24] = (float)kp[24]; vv[24] = (float)vp[24];

    const int i0 = half * 12;
    float qv[13];
    {
      const __bf16* qbase = qp + i0;  // row*56 + i0*2: 8B-aligned for i0 in {0,12}
      bf16x4 q0 = *(const bf16x4*)(qbase);
      bf16x4 q1 = *(const bf16x4*)(qbase + 4);
      bf16x4 q2 = *(const bf16x4*)(qbase + 8);
#pragma unroll
      for (int z = 0; z < 4; ++z) {
        qv[z] = (float)q0[z]; qv[4 + z] = (float)q1[z]; qv[8 + z] = (float)q2[z];
      }
      qv[12] = (float)qbase[12];
    }

#pragma unroll
    for (int z = 0; z < 13; ++z) {
      const float qi = qv[z];
      float s0 = 0.f, s1 = 0.f, s2 = 0.f, s3 = 0.f, s4 = 0.f;
      float o0 = 0.f, o1 = 0.f, o2 = 0.f, o3 = 0.f, o4 = 0.f;
#pragma unroll
      for (int g = 0; g < 5; ++g) {
        float e0 = fast_exp2(qi * kl[g * 5 + 0]);
        float e1 = fast_exp2(qi * kl[g * 5 + 1]);
        float e2 = fast_exp2(qi * kl[g * 5 + 2]);
        float e3 = fast_exp2(qi * kl[g * 5 + 3]);
        float e4 = fast_exp2(qi * kl[g * 5 + 4]);
        s0 += e0; o0 = __builtin_fmaf(e0, vv[g * 5 + 0], o0);
        s1 += e1; o1 = __builtin_fmaf(e1, vv[g * 5 + 1], o1);
        s2 += e2; o2 = __builtin_fmaf(e2, vv[g * 5 + 2], o2);
        s3 += e3; o3 = __builtin_fmaf(e3, vv[g * 5 + 3], o3);
        s4 += e4; o4 = __builtin_fmaf(e4, vv[g * 5 + 4], o4);
      }
      float ss = ((s0 + s1) + (s2 + s3)) + s4;
      float oo = ((o0 + o1) + (o2 + o3)) + o4;
      as_[(bl * 25 + i0 + z) * 32 + n] = __float2bfloat16(oo * __builtin_amdgcn_rcpf(ss));
    }
  }
  __syncthreads();

  // ---- phase 3: 1x1 conv via MFMA. M=100 rows, K=32 heads, N=32 ----
  {
    bf16x8 bw[2]; float ab[2];
#pragma unroll
    for (int nt2 = 0; nt2 < 2; ++nt2) {
      int n = nt2 * 16 + l15;
#pragma unroll
      for (int j = 0; j < 8; ++j)
        bw[nt2][j] = (__bf16)__float2bfloat16(attn_w[n * 32 + quad * 8 + j]);
      ab[nt2] = attn_b[n];
    }
    for (int mt = wave; mt < 7; mt += 4) {
      int row = mt * 16 + l15;
      int rc = row < 99 ? row : 99;
      bf16x8 af = *(const bf16x8*)(as_ + rc * 32 + quad * 8);
      f32x4 acc[2];
#pragma unroll
      for (int nt2 = 0; nt2 < 2; ++nt2)
        acc[nt2] = mfma16(af, bw[nt2], (f32x4){0.f, 0.f, 0.f, 0.f});
#pragma unroll
      for (int r = 0; r < 4; ++r) {
        int orow = mt * 16 + quad * 4 + r;
        if (orow < 100) {
          int ob = orow / 25, op = orow - ob * 25;
#pragma unroll
          for (int nt2 = 0; nt2 < 2; ++nt2)
            act[((size_t)(b0 + ob) * 25 + op) * 64 + 32 + nt2 * 16 + l15] =
                __float2bfloat16(fmaxf(acc[nt2][r] + ab[nt2], 0.f));
        }
      }
    }
  }
}

// ---------------- k2: fused dense chain — R2-proven 32-row/2-acc shape ----------------
// 256 blocks x 512 thr (8 waves = 2 wm x 4 wn); block = 32 rows.
__global__ __launch_bounds__(512) void k2(
    const __hip_bfloat16* __restrict__ act,
    const __hip_bfloat16* __restrict__ w1bp, const float* __restrict__ b1,
    const __hip_bfloat16* __restrict__ w2b, const float* __restrict__ b2,
    const float* __restrict__ w3, const float* __restrict__ b3,
    float* __restrict__ out) {
  const int t = threadIdx.x;
  const int lane = t & 63;
  const int wave = t >> 6;   // 0..7
  const int wm = wave >> 2;  // 0..1
  const int wn = wave & 3;   // 0..3
  const int l15 = lane & 15;
  const int quad = lane >> 4;  // 0..3
  const int b0 = blockIdx.x * 32;

  __shared__ __hip_bfloat16 C1s[32 * 136];
  __shared__ __hip_bfloat16 C2s[32 * 72];

  // ---- layer 1: [32,1600] x [128,1600]^T ----
  f32x4 acc0 = {0.f, 0.f, 0.f, 0.f};
  f32x4 acc1 = {0.f, 0.f, 0.f, 0.f};
  const __bf16* aptr  = (const __bf16*)act + (size_t)(b0 + wm * 16 + l15) * 1600 + quad * 8;
  const __bf16* bptr0 = (const __bf16*)w1bp + (size_t)(wn * 32 + l15) * 1600 + quad * 8;
  const __bf16* bptr1 = bptr0 + 16 * 1600;
#pragma unroll 5
  for (int k0 = 0; k0 < 1600; k0 += 32) {
    bf16x8 av  = *(const bf16x8*)(aptr + k0);
    bf16x8 bv0 = *(const bf16x8*)(bptr0 + k0);
    bf16x8 bv1 = *(const bf16x8*)(bptr1 + k0);
    acc0 = mfma16(av, bv0, acc0);
    acc1 = mfma16(av, bv1, acc1);
  }
  {
    const int col0 = wn * 32 + l15;
    const float bias0 = b1[col0];
    const float bias1 = b1[col0 + 16];
#pragma unroll
    for (int r = 0; r < 4; ++r) {
      const int row = wm * 16 + quad * 4 + r;
      C1s[row * 136 + col0]      = __float2bfloat16(fmaxf(acc0[r] + bias0, 0.f));
      C1s[row * 136 + col0 + 16] = __float2bfloat16(fmaxf(acc1[r] + bias1, 0.f));
    }
  }
  __syncthreads();

  // ---- layer 2: [32,128] x [64,128]^T ----
  f32x4 acc2 = {0.f, 0.f, 0.f, 0.f};
  {
    const __bf16* aL = (const __bf16*)C1s + (wm * 16 + l15) * 136 + quad * 8;
    const __bf16* bL = (const __bf16*)w2b + (wn * 16 + l15) * 128 + quad * 8;
#pragma unroll
    for (int k0 = 0; k0 < 128; k0 += 32)
      acc2 = mfma16(*(const bf16x8*)(aL + k0), *(const bf16x8*)(bL + k0), acc2);
  }
  {
    const int col = wn * 16 + l15;
    const float bias = b2[col];
#pragma unroll
    for (int r = 0; r < 4; ++r) {
      const int row = wm * 16 + quad * 4 + r;
      C2s[row * 72 + col] = __float2bfloat16(fmaxf(acc2[r] + bias, 0.f));
    }
  }
  __syncthreads();

  // ---- layer 3 (scalar, 160 outputs) ----
  if (t < 160) {
    const int row = t / 5;
    const int oc = t - row * 5;
    float s = b3[oc];
#pragma unroll
    for (int k = 0; k < 64; ++k)
      s += __bfloat162float(C2s[row * 72 + k]) * w3[oc * 64 + k];
    out[(size_t)(b0 + row) * 5 + oc] = s;
  }
}

extern "C" void kernel_launch(void* const* d_in, const int* in_sizes, int n_in,
                              void* d_out, int out_size, void* d_ws, size_t ws_size,
                              hipStream_t stream) {
  const float* x      = (const float*)d_in[0];
  const float* conv_w = (const float*)d_in[1];
  const float* conv_b = (const float*)d_in[2];
  const float* qkv_w  = (const float*)d_in[3];
  const float* qkv_b  = (const float*)d_in[4];
  const float* attn_w = (const float*)d_in[5];
  const float* attn_b = (const float*)d_in[6];
  const float* w1 = (const float*)d_in[7];
  const float* b1 = (const float*)d_in[8];
  const float* w2 = (const float*)d_in[9];
  const float* b2 = (const float*)d_in[10];
  const float* w3 = (const float*)d_in[11];
  const float* b3 = (const float*)d_in[12];
  float* out = (float*)d_out;

  // workspace layout (16B-aligned):
  //   act   [8192][25][64] bf16 : 26,214,400 B
  //   w1bp  [128][1600]    bf16 :    409,600 B
  //   w2b   [64][128]      bf16 :     16,384 B
  //   wqb   [128][64]      bf16 :     16,384 B  (k rows pre-scaled by log2e)
  //   biasb [128]          f32  :        512 B  (k entries pre-scaled by log2e)
  char* ws = (char*)d_ws;
  __hip_bfloat16* act  = (__hip_bfloat16*)ws;
  __hip_bfloat16* w1bp = (__hip_bfloat16*)(ws + 26214400);
  __hip_bfloat16* w2b  = (__hip_bfloat16*)(ws + 26624000);
  __hip_bfloat16* wqb  = (__hip_bfloat16*)(ws + 26640384);
  float*          biasb = (float*)(ws + 26656768);

  prep<<<dim3(800), dim3(256), 0, stream>>>(conv_w, conv_b, qkv_w, qkv_b,
                                            w1, w2, wqb, w1bp, w2b, biasb);
  k1<<<dim3(2048), dim3(256), 0, stream>>>(x, biasb, wqb, attn_w, attn_b, act);
  k2<<<dim3(256), dim3(512), 0, stream>>>(act, w1bp, b1, w2b, b2, w3, b3, out);
}

// Round 10
// 173.022 us; speedup vs baseline: 1.2407x; 1.0300x over previous
//
#include <hip/hip_runtime.h>
#include <hip/hip_bf16.h>
#include <cstdint>
#include <cstddef>

// B=8192, CIN=16, 6x6->5x5 (k=2 VALID), FM=64, DK=DV=NH=32 (dkh=1), HID=128, OUT=5.
// R10: k1 -> single-wave blocks (1 batch/block, 64 thr, 8192 blocks, ZERO barriers).
// Rationale: occupancy pinned ~19% across R4-R9 regardless of LDS/VGPR caps ->
// limiter is 4-wave barrier-phased blocks at 8 blocks/CU of grid. Single-wave
// blocks give ~20 independent resident waves/CU and remove all __syncthreads.
// act layout [b][pos][ch] (dense K-permuted); w1bp pre-permuted to match.

typedef __attribute__((ext_vector_type(4))) float f32x4;
typedef __attribute__((ext_vector_type(8))) __bf16 bf16x8;
typedef __attribute__((ext_vector_type(4))) __bf16 bf16x4;

#define LOG2E 1.4426950408889634f

// raw v_exp_f32 (2^x) — exp2f() lowers to the OCML wrapper (~4 extra VALU ops),
// measured as the R4->R6 attention regression (R7 confirmed the fix: -20us).
__device__ __forceinline__ float fast_exp2(float x) {
#if __has_builtin(__builtin_amdgcn_exp2f)
  return __builtin_amdgcn_exp2f(x);
#else
  return __expf(x * 0.6931471805599453f);
#endif
}

// v_mfma_f32_16x16x32_bf16 (bench-verified layout R2-R9):
// A: lane holds A[m=lane&15][k=quad*8+j]; B: W[n=lane&15][k=quad*8+j];
// C/D: col=lane&15, row=quad*4+reg.
__device__ __forceinline__ f32x4 mfma16(bf16x8 a, bf16x8 b, f32x4 c) {
  return __builtin_amdgcn_mfma_f32_16x16x32_bf16(a, b, c, 0, 0, 0);
}

// ---------------- prep: weight casts / permutes ----------------
// wqb rows 64..95 (k channels) and biasb[64..95] pre-scaled by LOG2E (R9-proven).
// wab = attn_w as bf16 [32][32] for phase-3 b128 fragment loads.
__global__ __launch_bounds__(256) void prep(
    const float* __restrict__ conv_w, const float* __restrict__ conv_b,
    const float* __restrict__ qkv_w,  const float* __restrict__ qkv_b,
    const float* __restrict__ attn_w,
    const float* __restrict__ w1, const float* __restrict__ w2,
    __hip_bfloat16* __restrict__ wqb, __hip_bfloat16* __restrict__ w1bp,
    __hip_bfloat16* __restrict__ w2b, float* __restrict__ biasb,
    __hip_bfloat16* __restrict__ wab) {
  int i = blockIdx.x * 256 + threadIdx.x;
  if (i < 128 * 1600) {
    int n = i / 1600, r = i - n * 1600;
    int c = r & 63, p = r >> 6;
    w1bp[i] = __float2bfloat16(w1[n * 1600 + c * 25 + p]);
  }
  if (i < 8192) {
    float w = (i < 2048) ? conv_w[i] : qkv_w[i - 2048];
    if (i >= 4096 && i < 6144) w *= LOG2E;  // k-channel rows 64..95
    wqb[i] = __float2bfloat16(w);
    w2b[i] = __float2bfloat16(w2[i]);
  }
  if (i < 1024) wab[i] = __float2bfloat16(attn_w[i]);
  if (i < 128) {
    float b = (i < 32) ? conv_b[i] : qkv_b[i - 32];
    if (i >= 64 && i < 96) b *= LOG2E;
    biasb[i] = b;
  }
}

// ---------------- k1: fused conv+qkv GEMM + attention + 1x1 conv, ONE WAVE ----------------
// 8192 blocks x 64 thr; block = 1 batch. GEMM M=25 (2 m-tiles). No __syncthreads.
// LDS (~7KB): region A (1600 B) = xs (phase1: x bf16, 576) / as_ (phase2/3, 25*32)
//             region B (5376 B) = qs [ch 0..95][pos stride 28] (k pre-scaled log2e)
__global__ __launch_bounds__(64) void k1(
    const float* __restrict__ x,
    const float* __restrict__ biasb,
    const __hip_bfloat16* __restrict__ wqb,
    const __hip_bfloat16* __restrict__ wab, const float* __restrict__ attn_b,
    __hip_bfloat16* __restrict__ act) {
  const int t = threadIdx.x;
  const int l15 = t & 15, quad = t >> 4;
  const int b = blockIdx.x;

  __shared__ __align__(16) char lds_raw[1600 + 5376];
  __bf16* xs  = (__bf16*)lds_raw;          // phase 1 (576 elems)
  __bf16* as_ = (__bf16*)lds_raw;          // phase 2/3 (800 elems, stride 32)
  __bf16* qs  = (__bf16*)(lds_raw + 1600); // q:0-31 k:32-63(x log2e) v:64-95, stride 28

  // ---- stage x -> bf16 LDS (576 floats, coalesced; same-wave ordering, no barrier) ----
  const float* xb = x + (size_t)b * 576;
#pragma unroll
  for (int i = 0; i < 9; ++i) {
    int f = t + i * 64;
    xs[f] = __float2bfloat16(xb[f]);
  }

  // ---- B-frags from bf16 wqb (L2-hot 16KB) + pre-scaled biases ----
  bf16x8 bfr[8][2];
#pragma unroll
  for (int nt = 0; nt < 8; ++nt)
#pragma unroll
    for (int ks = 0; ks < 2; ++ks)
      bfr[nt][ks] = *(const bf16x8*)((const __bf16*)wqb + (nt * 16 + l15) * 64 + ks * 32 + quad * 8);
  float bias[8];
#pragma unroll
  for (int nt = 0; nt < 8; ++nt) bias[nt] = biasb[nt * 16 + l15];

  // ---- phase 1: implicit GEMM, M=25, N=128, K=64; 2 m-tiles sequential ----
#pragma unroll
  for (int mt = 0; mt < 2; ++mt) {
    int row = mt * 16 + l15;
    int pos = row < 24 ? row : 24;
    int ii = pos / 5, jj = pos - ii * 5;
    const __bf16* xp = xs + ii * 6 + jj;
    bf16x8 af[2];
#pragma unroll
    for (int ks = 0; ks < 2; ++ks) {
      const __bf16* p0 = xp + (ks * 8 + quad * 2) * 36;
      bf16x8 a;
      a[0] = p0[0];  a[1] = p0[1];  a[2] = p0[6];  a[3] = p0[7];
      a[4] = p0[36]; a[5] = p0[37]; a[6] = p0[42]; a[7] = p0[43];
      af[ks] = a;
    }
    f32x4 acc[8];
#pragma unroll
    for (int nt = 0; nt < 8; ++nt) acc[nt] = (f32x4){0.f, 0.f, 0.f, 0.f};
#pragma unroll
    for (int ks = 0; ks < 2; ++ks)
#pragma unroll
      for (int nt = 0; nt < 8; ++nt)
        acc[nt] = mfma16(af[ks], bfr[nt][ks], acc[nt]);

#pragma unroll
    for (int r = 0; r < 4; ++r) {
      int orow = mt * 16 + quad * 4 + r;
      if (orow < 25) {
#pragma unroll
        for (int nt = 0; nt < 8; ++nt) {
          float v = acc[nt][r] + bias[nt];
          if (nt < 2) {  // conv_out ch 0..31 -> global with relu
            act[((size_t)b * 25 + orow) * 64 + nt * 16 + l15] =
                __float2bfloat16(fmaxf(v, 0.f));
          } else {       // qkv ch 0..95 -> LDS (k already log2e-scaled via weights)
            qs[((nt - 2) * 16 + l15) * 28 + orow] = __float2bfloat16(v);
          }
        }
      }
    }
  }

  // ---- phase 2: attention, dkh=1; e = 2^(q * k*log2e) via raw v_exp_f32;
  //      5 independent acc chains; lane n=t&31 owns head n, half=t>>5 splits i
  //      (i0 in {0,12}, i=12 computed by both halves with identical inputs). ----
  {
    const int n = t & 31, half = t >> 5;
    const __bf16* qp = qs + n * 28;
    const __bf16* kp = qs + (32 + n) * 28;
    const __bf16* vp = qs + (64 + n) * 28;
    float kl[25], vv[25];
#pragma unroll
    for (int c4 = 0; c4 < 6; ++c4) {
      bf16x4 bb = *(const bf16x4*)(kp + c4 * 4);
      bf16x4 cc = *(const bf16x4*)(vp + c4 * 4);
#pragma unroll
      for (int z = 0; z < 4; ++z) {
        kl[c4 * 4 + z] = (float)bb[z];
        vv[c4 * 4 + z] = (float)cc[z];
      }
    }
    kl[24] = (float)kp[24]; vv[24] = (float)vp[24];

    const int i0 = half * 12;
    float qv[13];
    {
      const __bf16* qbase = qp + i0;  // row*56 + i0*2: 8B-aligned for i0 in {0,12}
      bf16x4 q0 = *(const bf16x4*)(qbase);
      bf16x4 q1 = *(const bf16x4*)(qbase + 4);
      bf16x4 q2 = *(const bf16x4*)(qbase + 8);
#pragma unroll
      for (int z = 0; z < 4; ++z) {
        qv[z] = (float)q0[z]; qv[4 + z] = (float)q1[z]; qv[8 + z] = (float)q2[z];
      }
      qv[12] = (float)qbase[12];
    }

#pragma unroll
    for (int z = 0; z < 13; ++z) {
      const float qi = qv[z];
      float s0 = 0.f, s1 = 0.f, s2 = 0.f, s3 = 0.f, s4 = 0.f;
      float o0 = 0.f, o1 = 0.f, o2 = 0.f, o3 = 0.f, o4 = 0.f;
#pragma unroll
      for (int g = 0; g < 5; ++g) {
        float e0 = fast_exp2(qi * kl[g * 5 + 0]);
        float e1 = fast_exp2(qi * kl[g * 5 + 1]);
        float e2 = fast_exp2(qi * kl[g * 5 + 2]);
        float e3 = fast_exp2(qi * kl[g * 5 + 3]);
        float e4 = fast_exp2(qi * kl[g * 5 + 4]);
        s0 += e0; o0 = __builtin_fmaf(e0, vv[g * 5 + 0], o0);
        s1 += e1; o1 = __builtin_fmaf(e1, vv[g * 5 + 1], o1);
        s2 += e2; o2 = __builtin_fmaf(e2, vv[g * 5 + 2], o2);
        s3 += e3; o3 = __builtin_fmaf(e3, vv[g * 5 + 3], o3);
        s4 += e4; o4 = __builtin_fmaf(e4, vv[g * 5 + 4], o4);
      }
      float ss = ((s0 + s1) + (s2 + s3)) + s4;
      float oo = ((o0 + o1) + (o2 + o3)) + o4;
      as_[(i0 + z) * 32 + n] = __float2bfloat16(oo * __builtin_amdgcn_rcpf(ss));
    }
  }

  // ---- phase 3: 1x1 conv via MFMA. M=25 rows, K=32 heads, N=32 ----
  {
    bf16x8 bw[2]; float ab[2];
#pragma unroll
    for (int nt2 = 0; nt2 < 2; ++nt2) {
      int n = nt2 * 16 + l15;
      bw[nt2] = *(const bf16x8*)((const __bf16*)wab + n * 32 + quad * 8);
      ab[nt2] = attn_b[n];
    }
#pragma unroll
    for (int mt = 0; mt < 2; ++mt) {
      int row = mt * 16 + l15;
      int rc = row < 24 ? row : 24;
      bf16x8 af = *(const bf16x8*)(as_ + rc * 32 + quad * 8);
      f32x4 acc[2];
#pragma unroll
      for (int nt2 = 0; nt2 < 2; ++nt2)
        acc[nt2] = mfma16(af, bw[nt2], (f32x4){0.f, 0.f, 0.f, 0.f});
#pragma unroll
      for (int r = 0; r < 4; ++r) {
        int orow = mt * 16 + quad * 4 + r;
        if (orow < 25) {
#pragma unroll
          for (int nt2 = 0; nt2 < 2; ++nt2)
            act[((size_t)b * 25 + orow) * 64 + 32 + nt2 * 16 + l15] =
                __float2bfloat16(fmaxf(acc[nt2][r] + ab[nt2], 0.f));
        }
      }
    }
  }
}

// ---------------- k2: fused dense chain — R2-proven 32-row/2-acc shape ----------------
// 256 blocks x 512 thr (8 waves = 2 wm x 4 wn); block = 32 rows.
__global__ __launch_bounds__(512) void k2(
    const __hip_bfloat16* __restrict__ act,
    const __hip_bfloat16* __restrict__ w1bp, const float* __restrict__ b1,
    const __hip_bfloat16* __restrict__ w2b, const float* __restrict__ b2,
    const float* __restrict__ w3, const float* __restrict__ b3,
    float* __restrict__ out) {
  const int t = threadIdx.x;
  const int lane = t & 63;
  const int wave = t >> 6;   // 0..7
  const int wm = wave >> 2;  // 0..1
  const int wn = wave & 3;   // 0..3
  const int l15 = lane & 15;
  const int quad = lane >> 4;  // 0..3
  const int b0 = blockIdx.x * 32;

  __shared__ __hip_bfloat16 C1s[32 * 136];
  __shared__ __hip_bfloat16 C2s[32 * 72];

  // ---- layer 1: [32,1600] x [128,1600]^T ----
  f32x4 acc0 = {0.f, 0.f, 0.f, 0.f};
  f32x4 acc1 = {0.f, 0.f, 0.f, 0.f};
  const __bf16* aptr  = (const __bf16*)act + (size_t)(b0 + wm * 16 + l15) * 1600 + quad * 8;
  const __bf16* bptr0 = (const __bf16*)w1bp + (size_t)(wn * 32 + l15) * 1600 + quad * 8;
  const __bf16* bptr1 = bptr0 + 16 * 1600;
#pragma unroll 5
  for (int k0 = 0; k0 < 1600; k0 += 32) {
    bf16x8 av  = *(const bf16x8*)(aptr + k0);
    bf16x8 bv0 = *(const bf16x8*)(bptr0 + k0);
    bf16x8 bv1 = *(const bf16x8*)(bptr1 + k0);
    acc0 = mfma16(av, bv0, acc0);
    acc1 = mfma16(av, bv1, acc1);
  }
  {
    const int col0 = wn * 32 + l15;
    const float bias0 = b1[col0];
    const float bias1 = b1[col0 + 16];
#pragma unroll
    for (int r = 0; r < 4; ++r) {
      const int row = wm * 16 + quad * 4 + r;
      C1s[row * 136 + col0]      = __float2bfloat16(fmaxf(acc0[r] + bias0, 0.f));
      C1s[row * 136 + col0 + 16] = __float2bfloat16(fmaxf(acc1[r] + bias1, 0.f));
    }
  }
  __syncthreads();

  // ---- layer 2: [32,128] x [64,128]^T ----
  f32x4 acc2 = {0.f, 0.f, 0.f, 0.f};
  {
    const __bf16* aL = (const __bf16*)C1s + (wm * 16 + l15) * 136 + quad * 8;
    const __bf16* bL = (const __bf16*)w2b + (wn * 16 + l15) * 128 + quad * 8;
#pragma unroll
    for (int k0 = 0; k0 < 128; k0 += 32)
      acc2 = mfma16(*(const bf16x8*)(aL + k0), *(const bf16x8*)(bL + k0), acc2);
  }
  {
    const int col = wn * 16 + l15;
    const float bias = b2[col];
#pragma unroll
    for (int r = 0; r < 4; ++r) {
      const int row = wm * 16 + quad * 4 + r;
      C2s[row * 72 + col] = __float2bfloat16(fmaxf(acc2[r] + bias, 0.f));
    }
  }
  __syncthreads();

  // ---- layer 3 (scalar, 160 outputs) ----
  if (t < 160) {
    const int row = t / 5;
    const int oc = t - row * 5;
    float s = b3[oc];
#pragma unroll
    for (int k = 0; k < 64; ++k)
      s += __bfloat162float(C2s[row * 72 + k]) * w3[oc * 64 + k];
    out[(size_t)(b0 + row) * 5 + oc] = s;
  }
}

extern "C" void kernel_launch(void* const* d_in, const int* in_sizes, int n_in,
                              void* d_out, int out_size, void* d_ws, size_t ws_size,
                              hipStream_t stream) {
  const float* x      = (const float*)d_in[0];
  const float* conv_w = (const float*)d_in[1];
  const float* conv_b = (const float*)d_in[2];
  const float* qkv_w  = (const float*)d_in[3];
  const float* qkv_b  = (const float*)d_in[4];
  const float* attn_w = (const float*)d_in[5];
  const float* attn_b = (const float*)d_in[6];
  const float* w1 = (const float*)d_in[7];
  const float* b1 = (const float*)d_in[8];
  const float* w2 = (const float*)d_in[9];
  const float* b2 = (const float*)d_in[10];
  const float* w3 = (const float*)d_in[11];
  const float* b3 = (const float*)d_in[12];
  float* out = (float*)d_out;

  // workspace layout (16B-aligned):
  //   act   [8192][25][64] bf16 : 26,214,400 B
  //   w1bp  [128][1600]    bf16 :    409,600 B
  //   w2b   [64][128]      bf16 :     16,384 B
  //   wqb   [128][64]      bf16 :     16,384 B  (k rows pre-scaled by log2e)
  //   biasb [128]          f32  :        512 B  (k entries pre-scaled by log2e)
  //   wab   [32][32]       bf16 :      2,048 B
  char* ws = (char*)d_ws;
  __hip_bfloat16* act   = (__hip_bfloat16*)ws;
  __hip_bfloat16* w1bp  = (__hip_bfloat16*)(ws + 26214400);
  __hip_bfloat16* w2b   = (__hip_bfloat16*)(ws + 26624000);
  __hip_bfloat16* wqb   = (__hip_bfloat16*)(ws + 26640384);
  float*          biasb = (float*)(ws + 26656768);
  __hip_bfloat16* wab   = (__hip_bfloat16*)(ws + 26657280);

  prep<<<dim3(800), dim3(256), 0, stream>>>(conv_w, conv_b, qkv_w, qkv_b, attn_w,
                                            w1, w2, wqb, w1bp, w2b, biasb, wab);
  k1<<<dim3(8192), dim3(64), 0, stream>>>(x, biasb, wqb, wab, attn_b, act);
  k2<<<dim3(256), dim3(512), 0, stream>>>(act, w1bp, b1, w2b, b2, w3, b3, out);
}

// Round 11
// 171.902 us; speedup vs baseline: 1.2488x; 1.0065x over previous
//
#include <hip/hip_runtime.h>
#include <hip/hip_bf16.h>
#include <cstdint>
#include <cstddef>

// B=8192, CIN=16, 6x6->5x5 (k=2 VALID), FM=64, DK=DV=NH=32 (dkh=1), HID=128, OUT=5.
// R11 = R10 (k1 main path byte-identical) + prep rebalanced:
//   prep_small: only k1-main's inputs (wqb/biasb/wab, 9.3k elems, 17 blocks).
//   k1 tail blocks (8192..8331): k2's inputs (w1bp via coalesced LDS transpose, w2b).
// act layout [b][pos][ch] (dense K-permuted); w1bp pre-permuted to match.

typedef __attribute__((ext_vector_type(4))) float f32x4;
typedef __attribute__((ext_vector_type(8))) __bf16 bf16x8;
typedef __attribute__((ext_vector_type(4))) __bf16 bf16x4;

#define LOG2E 1.4426950408889634f

// raw v_exp_f32 (2^x) — exp2f() lowers to the OCML wrapper (~4 extra VALU ops),
// measured as the R4->R6 attention regression (R7 confirmed the fix: -20us).
__device__ __forceinline__ float fast_exp2(float x) {
#if __has_builtin(__builtin_amdgcn_exp2f)
  return __builtin_amdgcn_exp2f(x);
#else
  return __expf(x * 0.6931471805599453f);
#endif
}

// v_mfma_f32_16x16x32_bf16 (bench-verified layout R2-R10):
// A: lane holds A[m=lane&15][k=quad*8+j]; B: W[n=lane&15][k=quad*8+j];
// C/D: col=lane&15, row=quad*4+reg.
__device__ __forceinline__ f32x4 mfma16(bf16x8 a, bf16x8 b, f32x4 c) {
  return __builtin_amdgcn_mfma_f32_16x16x32_bf16(a, b, c, 0, 0, 0);
}

// ---------------- prep_small: ONLY what k1's main blocks read ----------------
// 17 blocks x 64 thr: wqb (k rows pre-scaled log2e), wab, biasb.
__global__ __launch_bounds__(64) void prep_small(
    const float* __restrict__ conv_w, const float* __restrict__ conv_b,
    const float* __restrict__ qkv_w,  const float* __restrict__ qkv_b,
    const float* __restrict__ attn_w,
    __hip_bfloat16* __restrict__ wqb, float* __restrict__ biasb,
    __hip_bfloat16* __restrict__ wab) {
  const int t = threadIdx.x, tb = blockIdx.x;
  if (tb < 16) {
#pragma unroll
    for (int j = 0; j < 8; ++j) {
      int i = tb * 512 + j * 64 + t;
      float w = (i < 2048) ? conv_w[i] : qkv_w[i - 2048];
      if (i >= 4096 && i < 6144) w *= LOG2E;  // k-channel rows 64..95
      wqb[i] = __float2bfloat16(w);
    }
  } else {
#pragma unroll
    for (int j = 0; j < 16; ++j) wab[j * 64 + t] = __float2bfloat16(attn_w[j * 64 + t]);
    for (int i = t; i < 128; i += 64) {
      float b = (i < 32) ? conv_b[i] : qkv_b[i - 32];
      if (i >= 64 && i < 96) b *= LOG2E;
      biasb[i] = b;
    }
  }
}

// ---------------- k1: fused conv+qkv GEMM + attention + 1x1 conv, ONE WAVE ----------------
// blocks 0..8191: main path (byte-identical to R10). blocks 8192..8331: k2-input prep.
// LDS (~7KB): region A (1600 B) = xs (phase1) / as_ (phase2/3) / fp32 row buf (tails)
//             region B (5376 B) = qs [ch 0..95][pos stride 28] (k pre-scaled log2e)
__global__ __launch_bounds__(64) void k1(
    const float* __restrict__ x,
    const float* __restrict__ biasb,
    const __hip_bfloat16* __restrict__ wqb,
    const __hip_bfloat16* __restrict__ wab, const float* __restrict__ attn_b,
    const float* __restrict__ w1, const float* __restrict__ w2,
    __hip_bfloat16* __restrict__ act,
    __hip_bfloat16* __restrict__ w1bp, __hip_bfloat16* __restrict__ w2b) {
  const int t = threadIdx.x;

  __shared__ __align__(16) char lds_raw[1600 + 5376];

  // ---- tail blocks: k2-input prep (runs in main-grid drain shadow) ----
  if (blockIdx.x >= 8192) {
    const int tb = blockIdx.x - 8192;
    if (tb < 128) {
      // w1bp row tb: coalesced fp32 read -> LDS -> coalesced permuted bf16 write.
      float* rowf = (float*)lds_raw;  // 1600 floats? 6400 B <= 6976 OK
      const float* wr = w1 + tb * 1600;
#pragma unroll
      for (int j = 0; j < 25; ++j) rowf[j * 64 + t] = wr[j * 64 + t];
      // single wave: same-wave LDS RAW ordered by lgkmcnt (no barrier needed)
      __hip_bfloat16* wo = w1bp + tb * 1600;
#pragma unroll
      for (int j = 0; j < 25; ++j) {
        // o = j*64 + t -> c = t (o&63), p = j (o>>6); read lds[c*25+p]: stride-25
        // dwords across lanes, gcd(25,32)=1 -> conflict-free.
        wo[j * 64 + t] = __float2bfloat16(rowf[t * 25 + j]);
      }
    } else {  // tb 128..131: w2b cast (2048 each, coalesced)
#pragma unroll
      for (int j = 0; j < 32; ++j) {
        int i = (tb - 128) * 2048 + j * 64 + t;
        w2b[i] = __float2bfloat16(w2[i]);
      }
    }
    return;
  }

  // ================= main path (byte-identical to R10) =================
  const int l15 = t & 15, quad = t >> 4;
  const int b = blockIdx.x;
  __bf16* xs  = (__bf16*)lds_raw;          // phase 1 (576 elems)
  __bf16* as_ = (__bf16*)lds_raw;          // phase 2/3 (800 elems, stride 32)
  __bf16* qs  = (__bf16*)(lds_raw + 1600); // q:0-31 k:32-63(x log2e) v:64-95, stride 28

  // ---- stage x -> bf16 LDS (576 floats, coalesced; same-wave ordering) ----
  const float* xb = x + (size_t)b * 576;
#pragma unroll
  for (int i = 0; i < 9; ++i) {
    int f = t + i * 64;
    xs[f] = __float2bfloat16(xb[f]);
  }

  // ---- B-frags from bf16 wqb (L2-hot 16KB) + pre-scaled biases ----
  bf16x8 bfr[8][2];
#pragma unroll
  for (int nt = 0; nt < 8; ++nt)
#pragma unroll
    for (int ks = 0; ks < 2; ++ks)
      bfr[nt][ks] = *(const bf16x8*)((const __bf16*)wqb + (nt * 16 + l15) * 64 + ks * 32 + quad * 8);
  float bias[8];
#pragma unroll
  for (int nt = 0; nt < 8; ++nt) bias[nt] = biasb[nt * 16 + l15];

  // ---- phase 1: implicit GEMM, M=25, N=128, K=64; 2 m-tiles sequential ----
#pragma unroll
  for (int mt = 0; mt < 2; ++mt) {
    int row = mt * 16 + l15;
    int pos = row < 24 ? row : 24;
    int ii = pos / 5, jj = pos - ii * 5;
    const __bf16* xp = xs + ii * 6 + jj;
    bf16x8 af[2];
#pragma unroll
    for (int ks = 0; ks < 2; ++ks) {
      const __bf16* p0 = xp + (ks * 8 + quad * 2) * 36;
      bf16x8 a;
      a[0] = p0[0];  a[1] = p0[1];  a[2] = p0[6];  a[3] = p0[7];
      a[4] = p0[36]; a[5] = p0[37]; a[6] = p0[42]; a[7] = p0[43];
      af[ks] = a;
    }
    f32x4 acc[8];
#pragma unroll
    for (int nt = 0; nt < 8; ++nt) acc[nt] = (f32x4){0.f, 0.f, 0.f, 0.f};
#pragma unroll
    for (int ks = 0; ks < 2; ++ks)
#pragma unroll
      for (int nt = 0; nt < 8; ++nt)
        acc[nt] = mfma16(af[ks], bfr[nt][ks], acc[nt]);

#pragma unroll
    for (int r = 0; r < 4; ++r) {
      int orow = mt * 16 + quad * 4 + r;
      if (orow < 25) {
#pragma unroll
        for (int nt = 0; nt < 8; ++nt) {
          float v = acc[nt][r] + bias[nt];
          if (nt < 2) {  // conv_out ch 0..31 -> global with relu
            act[((size_t)b * 25 + orow) * 64 + nt * 16 + l15] =
                __float2bfloat16(fmaxf(v, 0.f));
          } else {       // qkv ch 0..95 -> LDS (k already log2e-scaled via weights)
            qs[((nt - 2) * 16 + l15) * 28 + orow] = __float2bfloat16(v);
          }
        }
      }
    }
  }

  // ---- phase 2: attention, dkh=1; e = 2^(q * k*log2e) via raw v_exp_f32;
  //      5 independent acc chains; lane n=t&31 owns head n, half=t>>5 splits i. ----
  {
    const int n = t & 31, half = t >> 5;
    const __bf16* qp = qs + n * 28;
    const __bf16* kp = qs + (32 + n) * 28;
    const __bf16* vp = qs + (64 + n) * 28;
    float kl[25], vv[25];
#pragma unroll
    for (int c4 = 0; c4 < 6; ++c4) {
      bf16x4 bb = *(const bf16x4*)(kp + c4 * 4);
      bf16x4 cc = *(const bf16x4*)(vp + c4 * 4);
#pragma unroll
      for (int z = 0; z < 4; ++z) {
        kl[c4 * 4 + z] = (float)bb[z];
        vv[c4 * 4 + z] = (float)cc[z];
      }
    }
    kl[24] = (float)kp[24]; vv[24] = (float)vp[24];

    const int i0 = half * 12;
    float qv[13];
    {
      const __bf16* qbase = qp + i0;  // row*56 + i0*2: 8B-aligned for i0 in {0,12}
      bf16x4 q0 = *(const bf16x4*)(qbase);
      bf16x4 q1 = *(const bf16x4*)(qbase + 4);
      bf16x4 q2 = *(const bf16x4*)(qbase + 8);
#pragma unroll
      for (int z = 0; z < 4; ++z) {
        qv[z] = (float)q0[z]; qv[4 + z] = (float)q1[z]; qv[8 + z] = (float)q2[z];
      }
      qv[12] = (float)qbase[12];
    }

#pragma unroll
    for (int z = 0; z < 13; ++z) {
      const float qi = qv[z];
      float s0 = 0.f, s1 = 0.f, s2 = 0.f, s3 = 0.f, s4 = 0.f;
      float o0 = 0.f, o1 = 0.f, o2 = 0.f, o3 = 0.f, o4 = 0.f;
#pragma unroll
      for (int g = 0; g < 5; ++g) {
        float e0 = fast_exp2(qi * kl[g * 5 + 0]);
        float e1 = fast_exp2(qi * kl[g * 5 + 1]);
        float e2 = fast_exp2(qi * kl[g * 5 + 2]);
        float e3 = fast_exp2(qi * kl[g * 5 + 3]);
        float e4 = fast_exp2(qi * kl[g * 5 + 4]);
        s0 += e0; o0 = __builtin_fmaf(e0, vv[g * 5 + 0], o0);
        s1 += e1; o1 = __builtin_fmaf(e1, vv[g * 5 + 1], o1);
        s2 += e2; o2 = __builtin_fmaf(e2, vv[g * 5 + 2], o2);
        s3 += e3; o3 = __builtin_fmaf(e3, vv[g * 5 + 3], o3);
        s4 += e4; o4 = __builtin_fmaf(e4, vv[g * 5 + 4], o4);
      }
      float ss = ((s0 + s1) + (s2 + s3)) + s4;
      float oo = ((o0 + o1) + (o2 + o3)) + o4;
      as_[(i0 + z) * 32 + n] = __float2bfloat16(oo * __builtin_amdgcn_rcpf(ss));
    }
  }

  // ---- phase 3: 1x1 conv via MFMA. M=25 rows, K=32 heads, N=32 ----
  {
    bf16x8 bw[2]; float ab[2];
#pragma unroll
    for (int nt2 = 0; nt2 < 2; ++nt2) {
      int n = nt2 * 16 + l15;
      bw[nt2] = *(const bf16x8*)((const __bf16*)wab + n * 32 + quad * 8);
      ab[nt2] = attn_b[n];
    }
#pragma unroll
    for (int mt = 0; mt < 2; ++mt) {
      int row = mt * 16 + l15;
      int rc = row < 24 ? row : 24;
      bf16x8 af = *(const bf16x8*)(as_ + rc * 32 + quad * 8);
      f32x4 acc[2];
#pragma unroll
      for (int nt2 = 0; nt2 < 2; ++nt2)
        acc[nt2] = mfma16(af, bw[nt2], (f32x4){0.f, 0.f, 0.f, 0.f});
#pragma unroll
      for (int r = 0; r < 4; ++r) {
        int orow = mt * 16 + quad * 4 + r;
        if (orow < 25) {
#pragma unroll
          for (int nt2 = 0; nt2 < 2; ++nt2)
            act[((size_t)b * 25 + orow) * 64 + 32 + nt2 * 16 + l15] =
                __float2bfloat16(fmaxf(acc[nt2][r] + ab[nt2], 0.f));
        }
      }
    }
  }
}

// ---------------- k2: fused dense chain — R2-proven 32-row/2-acc shape (unchanged) ----------------
__global__ __launch_bounds__(512) void k2(
    const __hip_bfloat16* __restrict__ act,
    const __hip_bfloat16* __restrict__ w1bp, const float* __restrict__ b1,
    const __hip_bfloat16* __restrict__ w2b, const float* __restrict__ b2,
    const float* __restrict__ w3, const float* __restrict__ b3,
    float* __restrict__ out) {
  const int t = threadIdx.x;
  const int lane = t & 63;
  const int wave = t >> 6;   // 0..7
  const int wm = wave >> 2;  // 0..1
  const int wn = wave & 3;   // 0..3
  const int l15 = lane & 15;
  const int quad = lane >> 4;  // 0..3
  const int b0 = blockIdx.x * 32;

  __shared__ __hip_bfloat16 C1s[32 * 136];
  __shared__ __hip_bfloat16 C2s[32 * 72];

  // ---- layer 1: [32,1600] x [128,1600]^T ----
  f32x4 acc0 = {0.f, 0.f, 0.f, 0.f};
  f32x4 acc1 = {0.f, 0.f, 0.f, 0.f};
  const __bf16* aptr  = (const __bf16*)act + (size_t)(b0 + wm * 16 + l15) * 1600 + quad * 8;
  const __bf16* bptr0 = (const __bf16*)w1bp + (size_t)(wn * 32 + l15) * 1600 + quad * 8;
  const __bf16* bptr1 = bptr0 + 16 * 1600;
#pragma unroll 5
  for (int k0 = 0; k0 < 1600; k0 += 32) {
    bf16x8 av  = *(const bf16x8*)(aptr + k0);
    bf16x8 bv0 = *(const bf16x8*)(bptr0 + k0);
    bf16x8 bv1 = *(const bf16x8*)(bptr1 + k0);
    acc0 = mfma16(av, bv0, acc0);
    acc1 = mfma16(av, bv1, acc1);
  }
  {
    const int col0 = wn * 32 + l15;
    const float bias0 = b1[col0];
    const float bias1 = b1[col0 + 16];
#pragma unroll
    for (int r = 0; r < 4; ++r) {
      const int row = wm * 16 + quad * 4 + r;
      C1s[row * 136 + col0]      = __float2bfloat16(fmaxf(acc0[r] + bias0, 0.f));
      C1s[row * 136 + col0 + 16] = __float2bfloat16(fmaxf(acc1[r] + bias1, 0.f));
    }
  }
  __syncthreads();

  // ---- layer 2: [32,128] x [64,128]^T ----
  f32x4 acc2 = {0.f, 0.f, 0.f, 0.f};
  {
    const __bf16* aL = (const __bf16*)C1s + (wm * 16 + l15) * 136 + quad * 8;
    const __bf16* bL = (const __bf16*)w2b + (wn * 16 + l15) * 128 + quad * 8;
#pragma unroll
    for (int k0 = 0; k0 < 128; k0 += 32)
      acc2 = mfma16(*(const bf16x8*)(aL + k0), *(const bf16x8*)(bL + k0), acc2);
  }
  {
    const int col = wn * 16 + l15;
    const float bias = b2[col];
#pragma unroll
    for (int r = 0; r < 4; ++r) {
      const int row = wm * 16 + quad * 4 + r;
      C2s[row * 72 + col] = __float2bfloat16(fmaxf(acc2[r] + bias, 0.f));
    }
  }
  __syncthreads();

  // ---- layer 3 (scalar, 160 outputs) ----
  if (t < 160) {
    const int row = t / 5;
    const int oc = t - row * 5;
    float s = b3[oc];
#pragma unroll
    for (int k = 0; k < 64; ++k)
      s += __bfloat162float(C2s[row * 72 + k]) * w3[oc * 64 + k];
    out[(size_t)(b0 + row) * 5 + oc] = s;
  }
}

extern "C" void kernel_launch(void* const* d_in, const int* in_sizes, int n_in,
                              void* d_out, int out_size, void* d_ws, size_t ws_size,
                              hipStream_t stream) {
  const float* x      = (const float*)d_in[0];
  const float* conv_w = (const float*)d_in[1];
  const float* conv_b = (const float*)d_in[2];
  const float* qkv_w  = (const float*)d_in[3];
  const float* qkv_b  = (const float*)d_in[4];
  const float* attn_w = (const float*)d_in[5];
  const float* attn_b = (const float*)d_in[6];
  const float* w1 = (const float*)d_in[7];
  const float* b1 = (const float*)d_in[8];
  const float* w2 = (const float*)d_in[9];
  const float* b2 = (const float*)d_in[10];
  const float* w3 = (const float*)d_in[11];
  const float* b3 = (const float*)d_in[12];
  float* out = (float*)d_out;

  // workspace layout (16B-aligned):
  //   act   [8192][25][64] bf16 : 26,214,400 B
  //   w1bp  [128][1600]    bf16 :    409,600 B  (written by k1 tail blocks 0..127)
  //   w2b   [64][128]      bf16 :     16,384 B  (written by k1 tail blocks 128..131)
  //   wqb   [128][64]      bf16 :     16,384 B  (k rows pre-scaled by log2e)
  //   biasb [128]          f32  :        512 B  (k entries pre-scaled by log2e)
  //   wab   [32][32]       bf16 :      2,048 B
  char* ws = (char*)d_ws;
  __hip_bfloat16* act   = (__hip_bfloat16*)ws;
  __hip_bfloat16* w1bp  = (__hip_bfloat16*)(ws + 26214400);
  __hip_bfloat16* w2b   = (__hip_bfloat16*)(ws + 26624000);
  __hip_bfloat16* wqb   = (__hip_bfloat16*)(ws + 26640384);
  float*          biasb = (float*)(ws + 26656768);
  __hip_bfloat16* wab   = (__hip_bfloat16*)(ws + 26657280);

  prep_small<<<dim3(17), dim3(64), 0, stream>>>(conv_w, conv_b, qkv_w, qkv_b, attn_w,
                                                wqb, biasb, wab);
  k1<<<dim3(8192 + 132), dim3(64), 0, stream>>>(x, biasb, wqb, wab, attn_b,
                                                w1, w2, act, w1bp, w2b);
  k2<<<dim3(256), dim3(512), 0, stream>>>(act, w1bp, b1, w2b, b2, w3, b3, out);
}

// Round 12
// 166.986 us; speedup vs baseline: 1.2856x; 1.0294x over previous
//
#include <hip/hip_runtime.h>
#include <hip/hip_bf16.h>
#include <cstdint>
#include <cstddef>

// B=8192, CIN=16, 6x6->5x5 (k=2 VALID), FM=64, DK=DV=NH=32 (dkh=1), HID=128, OUT=5.
// R12 = R11 with k1 restructured: 2 batches/block (128 thr = 2 waves), each wave
// runs the R11 per-wave program on a PRIVATE 7KB LDS region — still zero barriers.
// Rationale: CU workgroup-slot cap (~16 wg/CU) bound occupancy with 64-thr blocks;
// doubling waves/wg doubles resident waves without touching per-wave code.
// act layout [b][pos][ch] (dense K-permuted); w1bp pre-permuted to match.

typedef __attribute__((ext_vector_type(4))) float f32x4;
typedef __attribute__((ext_vector_type(8))) __bf16 bf16x8;
typedef __attribute__((ext_vector_type(4))) __bf16 bf16x4;

#define LOG2E 1.4426950408889634f

// raw v_exp_f32 (2^x) — exp2f() lowers to the OCML wrapper (~4 extra VALU ops),
// measured as the R4->R6 attention regression (R7 confirmed the fix: -20us).
__device__ __forceinline__ float fast_exp2(float x) {
#if __has_builtin(__builtin_amdgcn_exp2f)
  return __builtin_amdgcn_exp2f(x);
#else
  return __expf(x * 0.6931471805599453f);
#endif
}

// v_mfma_f32_16x16x32_bf16 (bench-verified layout R2-R11):
// A: lane holds A[m=lane&15][k=quad*8+j]; B: W[n=lane&15][k=quad*8+j];
// C/D: col=lane&15, row=quad*4+reg.
__device__ __forceinline__ f32x4 mfma16(bf16x8 a, bf16x8 b, f32x4 c) {
  return __builtin_amdgcn_mfma_f32_16x16x32_bf16(a, b, c, 0, 0, 0);
}

// ---------------- prep_small: ONLY what k1's main blocks read (unchanged R11) ----------------
__global__ __launch_bounds__(64) void prep_small(
    const float* __restrict__ conv_w, const float* __restrict__ conv_b,
    const float* __restrict__ qkv_w,  const float* __restrict__ qkv_b,
    const float* __restrict__ attn_w,
    __hip_bfloat16* __restrict__ wqb, float* __restrict__ biasb,
    __hip_bfloat16* __restrict__ wab) {
  const int t = threadIdx.x, tb = blockIdx.x;
  if (tb < 16) {
#pragma unroll
    for (int j = 0; j < 8; ++j) {
      int i = tb * 512 + j * 64 + t;
      float w = (i < 2048) ? conv_w[i] : qkv_w[i - 2048];
      if (i >= 4096 && i < 6144) w *= LOG2E;  // k-channel rows 64..95
      wqb[i] = __float2bfloat16(w);
    }
  } else {
#pragma unroll
    for (int j = 0; j < 16; ++j) wab[j * 64 + t] = __float2bfloat16(attn_w[j * 64 + t]);
    for (int i = t; i < 128; i += 64) {
      float b = (i < 32) ? conv_b[i] : qkv_b[i - 32];
      if (i >= 64 && i < 96) b *= LOG2E;
      biasb[i] = b;
    }
  }
}

// ---------------- k1: fused conv+qkv GEMM + attention + 1x1 conv ----------------
// Main blocks 0..4095: 2 waves x 1 batch each, private LDS region, no barriers.
// Tail blocks 4096..4161: 2 waves x 1 prep unit each (w1bp rows / w2b cast).
__global__ __launch_bounds__(128) void k1(
    const float* __restrict__ x,
    const float* __restrict__ biasb,
    const __hip_bfloat16* __restrict__ wqb,
    const __hip_bfloat16* __restrict__ wab, const float* __restrict__ attn_b,
    const float* __restrict__ w1, const float* __restrict__ w2,
    __hip_bfloat16* __restrict__ act,
    __hip_bfloat16* __restrict__ w1bp, __hip_bfloat16* __restrict__ w2b) {
  const int t = threadIdx.x & 63;   // lane within wave
  const int wv = threadIdx.x >> 6;  // wave 0/1 in block

  __shared__ __align__(16) char lds_raw[2 * 7168];
  char* my = lds_raw + wv * 7168;   // private per-wave region

  // ---- tail blocks: k2-input prep (runs in main-grid drain shadow) ----
  if (blockIdx.x >= 4096) {
    const int u = (blockIdx.x - 4096) * 2 + wv;  // unit 0..131
    if (u < 128) {
      // w1bp row u: coalesced fp32 read -> LDS -> coalesced permuted bf16 write.
      float* rowf = (float*)my;  // 6400 B <= 7168 OK
      const float* wr = w1 + u * 1600;
#pragma unroll
      for (int j = 0; j < 25; ++j) rowf[j * 64 + t] = wr[j * 64 + t];
      // single wave: same-wave LDS RAW ordered by lgkmcnt (no barrier needed)
      __hip_bfloat16* wo = w1bp + u * 1600;
#pragma unroll
      for (int j = 0; j < 25; ++j) {
        // read lds[t*25+j]: stride-25 dwords, gcd(25,32)=1 -> conflict-free
        wo[j * 64 + t] = __float2bfloat16(rowf[t * 25 + j]);
      }
    } else if (u < 132) {  // w2b cast (2048 each, coalesced)
#pragma unroll
      for (int j = 0; j < 32; ++j) {
        int i = (u - 128) * 2048 + j * 64 + t;
        w2b[i] = __float2bfloat16(w2[i]);
      }
    }
    return;
  }

  // ================= main path (per-wave code identical to R11) =================
  const int l15 = t & 15, quad = t >> 4;
  const int b = blockIdx.x * 2 + wv;
  __bf16* xs  = (__bf16*)my;          // phase 1 (576 elems)
  __bf16* as_ = (__bf16*)my;          // phase 2/3 (800 elems, stride 32)
  __bf16* qs  = (__bf16*)(my + 1600); // q:0-31 k:32-63(x log2e) v:64-95, stride 28

  // ---- stage x -> bf16 LDS (576 floats, coalesced; same-wave ordering) ----
  const float* xb = x + (size_t)b * 576;
#pragma unroll
  for (int i = 0; i < 9; ++i) {
    int f = t + i * 64;
    xs[f] = __float2bfloat16(xb[f]);
  }

  // ---- B-frags from bf16 wqb (L2-hot 16KB) + pre-scaled biases ----
  bf16x8 bfr[8][2];
#pragma unroll
  for (int nt = 0; nt < 8; ++nt)
#pragma unroll
    for (int ks = 0; ks < 2; ++ks)
      bfr[nt][ks] = *(const bf16x8*)((const __bf16*)wqb + (nt * 16 + l15) * 64 + ks * 32 + quad * 8);
  float bias[8];
#pragma unroll
  for (int nt = 0; nt < 8; ++nt) bias[nt] = biasb[nt * 16 + l15];

  // ---- phase 1: implicit GEMM, M=25, N=128, K=64; 2 m-tiles sequential ----
#pragma unroll
  for (int mt = 0; mt < 2; ++mt) {
    int row = mt * 16 + l15;
    int pos = row < 24 ? row : 24;
    int ii = pos / 5, jj = pos - ii * 5;
    const __bf16* xp = xs + ii * 6 + jj;
    bf16x8 af[2];
#pragma unroll
    for (int ks = 0; ks < 2; ++ks) {
      const __bf16* p0 = xp + (ks * 8 + quad * 2) * 36;
      bf16x8 a;
      a[0] = p0[0];  a[1] = p0[1];  a[2] = p0[6];  a[3] = p0[7];
      a[4] = p0[36]; a[5] = p0[37]; a[6] = p0[42]; a[7] = p0[43];
      af[ks] = a;
    }
    f32x4 acc[8];
#pragma unroll
    for (int nt = 0; nt < 8; ++nt) acc[nt] = (f32x4){0.f, 0.f, 0.f, 0.f};
#pragma unroll
    for (int ks = 0; ks < 2; ++ks)
#pragma unroll
      for (int nt = 0; nt < 8; ++nt)
        acc[nt] = mfma16(af[ks], bfr[nt][ks], acc[nt]);

#pragma unroll
    for (int r = 0; r < 4; ++r) {
      int orow = mt * 16 + quad * 4 + r;
      if (orow < 25) {
#pragma unroll
        for (int nt = 0; nt < 8; ++nt) {
          float v = acc[nt][r] + bias[nt];
          if (nt < 2) {  // conv_out ch 0..31 -> global with relu
            act[((size_t)b * 25 + orow) * 64 + nt * 16 + l15] =
                __float2bfloat16(fmaxf(v, 0.f));
          } else {       // qkv ch 0..95 -> LDS (k already log2e-scaled via weights)
            qs[((nt - 2) * 16 + l15) * 28 + orow] = __float2bfloat16(v);
          }
        }
      }
    }
  }

  // ---- phase 2: attention, dkh=1; e = 2^(q * k*log2e) via raw v_exp_f32;
  //      5 independent acc chains; lane n=t&31 owns head n, half=t>>5 splits i. ----
  {
    const int n = t & 31, half = t >> 5;
    const __bf16* qp = qs + n * 28;
    const __bf16* kp = qs + (32 + n) * 28;
    const __bf16* vp = qs + (64 + n) * 28;
    float kl[25], vv[25];
#pragma unroll
    for (int c4 = 0; c4 < 6; ++c4) {
      bf16x4 bb = *(const bf16x4*)(kp + c4 * 4);
      bf16x4 cc = *(const bf16x4*)(vp + c4 * 4);
#pragma unroll
      for (int z = 0; z < 4; ++z) {
        kl[c4 * 4 + z] = (float)bb[z];
        vv[c4 * 4 + z] = (float)cc[z];
      }
    }
    kl[24] = (float)kp[24]; vv[24] = (float)vp[24];

    const int i0 = half * 12;
    float qv[13];
    {
      const __bf16* qbase = qp + i0;  // row*56 + i0*2: 8B-aligned for i0 in {0,12}
      bf16x4 q0 = *(const bf16x4*)(qbase);
      bf16x4 q1 = *(const bf16x4*)(qbase + 4);
      bf16x4 q2 = *(const bf16x4*)(qbase + 8);
#pragma unroll
      for (int z = 0; z < 4; ++z) {
        qv[z] = (float)q0[z]; qv[4 + z] = (float)q1[z]; qv[8 + z] = (float)q2[z];
      }
      qv[12] = (float)qbase[12];
    }

#pragma unroll
    for (int z = 0; z < 13; ++z) {
      const float qi = qv[z];
      float s0 = 0.f, s1 = 0.f, s2 = 0.f, s3 = 0.f, s4 = 0.f;
      float o0 = 0.f, o1 = 0.f, o2 = 0.f, o3 = 0.f, o4 = 0.f;
#pragma unroll
      for (int g = 0; g < 5; ++g) {
        float e0 = fast_exp2(qi * kl[g * 5 + 0]);
        float e1 = fast_exp2(qi * kl[g * 5 + 1]);
        float e2 = fast_exp2(qi * kl[g * 5 + 2]);
        float e3 = fast_exp2(qi * kl[g * 5 + 3]);
        float e4 = fast_exp2(qi * kl[g * 5 + 4]);
        s0 += e0; o0 = __builtin_fmaf(e0, vv[g * 5 + 0], o0);
        s1 += e1; o1 = __builtin_fmaf(e1, vv[g * 5 + 1], o1);
        s2 += e2; o2 = __builtin_fmaf(e2, vv[g * 5 + 2], o2);
        s3 += e3; o3 = __builtin_fmaf(e3, vv[g * 5 + 3], o3);
        s4 += e4; o4 = __builtin_fmaf(e4, vv[g * 5 + 4], o4);
      }
      float ss = ((s0 + s1) + (s2 + s3)) + s4;
      float oo = ((o0 + o1) + (o2 + o3)) + o4;
      as_[(i0 + z) * 32 + n] = __float2bfloat16(oo * __builtin_amdgcn_rcpf(ss));
    }
  }

  // ---- phase 3: 1x1 conv via MFMA. M=25 rows, K=32 heads, N=32 ----
  {
    bf16x8 bw[2]; float ab[2];
#pragma unroll
    for (int nt2 = 0; nt2 < 2; ++nt2) {
      int n = nt2 * 16 + l15;
      bw[nt2] = *(const bf16x8*)((const __bf16*)wab + n * 32 + quad * 8);
      ab[nt2] = attn_b[n];
    }
#pragma unroll
    for (int mt = 0; mt < 2; ++mt) {
      int row = mt * 16 + l15;
      int rc = row < 24 ? row : 24;
      bf16x8 af = *(const bf16x8*)(as_ + rc * 32 + quad * 8);
      f32x4 acc[2];
#pragma unroll
      for (int nt2 = 0; nt2 < 2; ++nt2)
        acc[nt2] = mfma16(af, bw[nt2], (f32x4){0.f, 0.f, 0.f, 0.f});
#pragma unroll
      for (int r = 0; r < 4; ++r) {
        int orow = mt * 16 + quad * 4 + r;
        if (orow < 25) {
#pragma unroll
          for (int nt2 = 0; nt2 < 2; ++nt2)
            act[((size_t)b * 25 + orow) * 64 + 32 + nt2 * 16 + l15] =
                __float2bfloat16(fmaxf(acc[nt2][r] + ab[nt2], 0.f));
        }
      }
    }
  }
}

// ---------------- k2: fused dense chain — R2-proven 32-row/2-acc shape (unchanged) ----------------
__global__ __launch_bounds__(512) void k2(
    const __hip_bfloat16* __restrict__ act,
    const __hip_bfloat16* __restrict__ w1bp, const float* __restrict__ b1,
    const __hip_bfloat16* __restrict__ w2b, const float* __restrict__ b2,
    const float* __restrict__ w3, const float* __restrict__ b3,
    float* __restrict__ out) {
  const int t = threadIdx.x;
  const int lane = t & 63;
  const int wave = t >> 6;   // 0..7
  const int wm = wave >> 2;  // 0..1
  const int wn = wave & 3;   // 0..3
  const int l15 = lane & 15;
  const int quad = lane >> 4;  // 0..3
  const int b0 = blockIdx.x * 32;

  __shared__ __hip_bfloat16 C1s[32 * 136];
  __shared__ __hip_bfloat16 C2s[32 * 72];

  // ---- layer 1: [32,1600] x [128,1600]^T ----
  f32x4 acc0 = {0.f, 0.f, 0.f, 0.f};
  f32x4 acc1 = {0.f, 0.f, 0.f, 0.f};
  const __bf16* aptr  = (const __bf16*)act + (size_t)(b0 + wm * 16 + l15) * 1600 + quad * 8;
  const __bf16* bptr0 = (const __bf16*)w1bp + (size_t)(wn * 32 + l15) * 1600 + quad * 8;
  const __bf16* bptr1 = bptr0 + 16 * 1600;
#pragma unroll 5
  for (int k0 = 0; k0 < 1600; k0 += 32) {
    bf16x8 av  = *(const bf16x8*)(aptr + k0);
    bf16x8 bv0 = *(const bf16x8*)(bptr0 + k0);
    bf16x8 bv1 = *(const bf16x8*)(bptr1 + k0);
    acc0 = mfma16(av, bv0, acc0);
    acc1 = mfma16(av, bv1, acc1);
  }
  {
    const int col0 = wn * 32 + l15;
    const float bias0 = b1[col0];
    const float bias1 = b1[col0 + 16];
#pragma unroll
    for (int r = 0; r < 4; ++r) {
      const int row = wm * 16 + quad * 4 + r;
      C1s[row * 136 + col0]      = __float2bfloat16(fmaxf(acc0[r] + bias0, 0.f));
      C1s[row * 136 + col0 + 16] = __float2bfloat16(fmaxf(acc1[r] + bias1, 0.f));
    }
  }
  __syncthreads();

  // ---- layer 2: [32,128] x [64,128]^T ----
  f32x4 acc2 = {0.f, 0.f, 0.f, 0.f};
  {
    const __bf16* aL = (const __bf16*)C1s + (wm * 16 + l15) * 136 + quad * 8;
    const __bf16* bL = (const __bf16*)w2b + (wn * 16 + l15) * 128 + quad * 8;
#pragma unroll
    for (int k0 = 0; k0 < 128; k0 += 32)
      acc2 = mfma16(*(const bf16x8*)(aL + k0), *(const bf16x8*)(bL + k0), acc2);
  }
  {
    const int col = wn * 16 + l15;
    const float bias = b2[col];
#pragma unroll
    for (int r = 0; r < 4; ++r) {
      const int row = wm * 16 + quad * 4 + r;
      C2s[row * 72 + col] = __float2bfloat16(fmaxf(acc2[r] + bias, 0.f));
    }
  }
  __syncthreads();

  // ---- layer 3 (scalar, 160 outputs) ----
  if (t < 160) {
    const int row = t / 5;
    const int oc = t - row * 5;
    float s = b3[oc];
#pragma unroll
    for (int k = 0; k < 64; ++k)
      s += __bfloat162float(C2s[row * 72 + k]) * w3[oc * 64 + k];
    out[(size_t)(b0 + row) * 5 + oc] = s;
  }
}

extern "C" void kernel_launch(void* const* d_in, const int* in_sizes, int n_in,
                              void* d_out, int out_size, void* d_ws, size_t ws_size,
                              hipStream_t stream) {
  const float* x      = (const float*)d_in[0];
  const float* conv_w = (const float*)d_in[1];
  const float* conv_b = (const float*)d_in[2];
  const float* qkv_w  = (const float*)d_in[3];
  const float* qkv_b  = (const float*)d_in[4];
  const float* attn_w = (const float*)d_in[5];
  const float* attn_b = (const float*)d_in[6];
  const float* w1 = (const float*)d_in[7];
  const float* b1 = (const float*)d_in[8];
  const float* w2 = (const float*)d_in[9];
  const float* b2 = (const float*)d_in[10];
  const float* w3 = (const float*)d_in[11];
  const float* b3 = (const float*)d_in[12];
  float* out = (float*)d_out;

  // workspace layout (16B-aligned):
  //   act   [8192][25][64] bf16 : 26,214,400 B
  //   w1bp  [128][1600]    bf16 :    409,600 B  (written by k1 tail units 0..127)
  //   w2b   [64][128]      bf16 :     16,384 B  (written by k1 tail units 128..131)
  //   wqb   [128][64]      bf16 :     16,384 B  (k rows pre-scaled by log2e)
  //   biasb [128]          f32  :        512 B  (k entries pre-scaled by log2e)
  //   wab   [32][32]       bf16 :      2,048 B
  char* ws = (char*)d_ws;
  __hip_bfloat16* act   = (__hip_bfloat16*)ws;
  __hip_bfloat16* w1bp  = (__hip_bfloat16*)(ws + 26214400);
  __hip_bfloat16* w2b   = (__hip_bfloat16*)(ws + 26624000);
  __hip_bfloat16* wqb   = (__hip_bfloat16*)(ws + 26640384);
  float*          biasb = (float*)(ws + 26656768);
  __hip_bfloat16* wab   = (__hip_bfloat16*)(ws + 26657280);

  prep_small<<<dim3(17), dim3(64), 0, stream>>>(conv_w, conv_b, qkv_w, qkv_b, attn_w,
                                                wqb, biasb, wab);
  k1<<<dim3(4096 + 66), dim3(128), 0, stream>>>(x, biasb, wqb, wab, attn_b,
                                                w1, w2, act, w1bp, w2b);
  k2<<<dim3(256), dim3(512), 0, stream>>>(act, w1bp, b1, w2b, b2, w3, b3, out);
}

// Round 13
// 165.269 us; speedup vs baseline: 1.2989x; 1.0104x over previous
//
#include <hip/hip_runtime.h>
#include <hip/hip_bf16.h>
#include <cstdint>
#include <cstddef>

// B=8192, CIN=16, 6x6->5x5 (k=2 VALID), FM=64, DK=DV=NH=32 (dkh=1), HID=128, OUT=5.
// R13 = R12 with 4 waves/block (4 batches, private 7KB LDS regions, zero barriers).
// Tests the ~8-wg/CU slot-cap hypothesis: if wg slots bound occupancy, 4-wave
// blocks double resident waves (8 wg x 4 = 32 waves/CU) without code changes.
// act layout [b][pos][ch] (dense K-permuted); w1bp pre-permuted to match.

typedef __attribute__((ext_vector_type(4))) float f32x4;
typedef __attribute__((ext_vector_type(8))) __bf16 bf16x8;
typedef __attribute__((ext_vector_type(4))) __bf16 bf16x4;

#define LOG2E 1.4426950408889634f

// raw v_exp_f32 (2^x) — exp2f() lowers to the OCML wrapper (~4 extra VALU ops),
// measured as the R4->R6 attention regression (R7 confirmed the fix: -20us).
__device__ __forceinline__ float fast_exp2(float x) {
#if __has_builtin(__builtin_amdgcn_exp2f)
  return __builtin_amdgcn_exp2f(x);
#else
  return __expf(x * 0.6931471805599453f);
#endif
}

// v_mfma_f32_16x16x32_bf16 (bench-verified layout R2-R12):
// A: lane holds A[m=lane&15][k=quad*8+j]; B: W[n=lane&15][k=quad*8+j];
// C/D: col=lane&15, row=quad*4+reg.
__device__ __forceinline__ f32x4 mfma16(bf16x8 a, bf16x8 b, f32x4 c) {
  return __builtin_amdgcn_mfma_f32_16x16x32_bf16(a, b, c, 0, 0, 0);
}

// ---------------- prep_small: ONLY what k1's main blocks read (unchanged R11/R12) ----------------
__global__ __launch_bounds__(64) void prep_small(
    const float* __restrict__ conv_w, const float* __restrict__ conv_b,
    const float* __restrict__ qkv_w,  const float* __restrict__ qkv_b,
    const float* __restrict__ attn_w,
    __hip_bfloat16* __restrict__ wqb, float* __restrict__ biasb,
    __hip_bfloat16* __restrict__ wab) {
  const int t = threadIdx.x, tb = blockIdx.x;
  if (tb < 16) {
#pragma unroll
    for (int j = 0; j < 8; ++j) {
      int i = tb * 512 + j * 64 + t;
      float w = (i < 2048) ? conv_w[i] : qkv_w[i - 2048];
      if (i >= 4096 && i < 6144) w *= LOG2E;  // k-channel rows 64..95
      wqb[i] = __float2bfloat16(w);
    }
  } else {
#pragma unroll
    for (int j = 0; j < 16; ++j) wab[j * 64 + t] = __float2bfloat16(attn_w[j * 64 + t]);
    for (int i = t; i < 128; i += 64) {
      float b = (i < 32) ? conv_b[i] : qkv_b[i - 32];
      if (i >= 64 && i < 96) b *= LOG2E;
      biasb[i] = b;
    }
  }
}

// ---------------- k1: fused conv+qkv GEMM + attention + 1x1 conv ----------------
// Main blocks 0..2047: 4 waves x 1 batch each, private LDS region, no barriers.
// Tail blocks 2048..2080: 4 waves x 1 prep unit each (w1bp rows / w2b cast).
__global__ __launch_bounds__(256) void k1(
    const float* __restrict__ x,
    const float* __restrict__ biasb,
    const __hip_bfloat16* __restrict__ wqb,
    const __hip_bfloat16* __restrict__ wab, const float* __restrict__ attn_b,
    const float* __restrict__ w1, const float* __restrict__ w2,
    __hip_bfloat16* __restrict__ act,
    __hip_bfloat16* __restrict__ w1bp, __hip_bfloat16* __restrict__ w2b) {
  const int t = threadIdx.x & 63;   // lane within wave
  const int wv = threadIdx.x >> 6;  // wave 0..3 in block

  __shared__ __align__(16) char lds_raw[4 * 7168];
  char* my = lds_raw + wv * 7168;   // private per-wave region

  // ---- tail blocks: k2-input prep (runs in main-grid drain shadow) ----
  if (blockIdx.x >= 2048) {
    const int u = (blockIdx.x - 2048) * 4 + wv;  // unit 0..131
    if (u < 128) {
      // w1bp row u: coalesced fp32 read -> LDS -> coalesced permuted bf16 write.
      float* rowf = (float*)my;  // 6400 B <= 7168 OK
      const float* wr = w1 + u * 1600;
#pragma unroll
      for (int j = 0; j < 25; ++j) rowf[j * 64 + t] = wr[j * 64 + t];
      // single wave: same-wave LDS RAW ordered by lgkmcnt (no barrier needed)
      __hip_bfloat16* wo = w1bp + u * 1600;
#pragma unroll
      for (int j = 0; j < 25; ++j) {
        // read lds[t*25+j]: stride-25 dwords, gcd(25,32)=1 -> conflict-free
        wo[j * 64 + t] = __float2bfloat16(rowf[t * 25 + j]);
      }
    } else if (u < 132) {  // w2b cast (2048 each, coalesced)
#pragma unroll
      for (int j = 0; j < 32; ++j) {
        int i = (u - 128) * 2048 + j * 64 + t;
        w2b[i] = __float2bfloat16(w2[i]);
      }
    }
    return;
  }

  // ================= main path (per-wave code identical to R12) =================
  const int l15 = t & 15, quad = t >> 4;
  const int b = blockIdx.x * 4 + wv;
  __bf16* xs  = (__bf16*)my;          // phase 1 (576 elems)
  __bf16* as_ = (__bf16*)my;          // phase 2/3 (800 elems, stride 32)
  __bf16* qs  = (__bf16*)(my + 1600); // q:0-31 k:32-63(x log2e) v:64-95, stride 28

  // ---- stage x -> bf16 LDS (576 floats, coalesced; same-wave ordering) ----
  const float* xb = x + (size_t)b * 576;
#pragma unroll
  for (int i = 0; i < 9; ++i) {
    int f = t + i * 64;
    xs[f] = __float2bfloat16(xb[f]);
  }

  // ---- B-frags from bf16 wqb (L2-hot 16KB) + pre-scaled biases ----
  bf16x8 bfr[8][2];
#pragma unroll
  for (int nt = 0; nt < 8; ++nt)
#pragma unroll
    for (int ks = 0; ks < 2; ++ks)
      bfr[nt][ks] = *(const bf16x8*)((const __bf16*)wqb + (nt * 16 + l15) * 64 + ks * 32 + quad * 8);
  float bias[8];
#pragma unroll
  for (int nt = 0; nt < 8; ++nt) bias[nt] = biasb[nt * 16 + l15];

  // ---- phase 1: implicit GEMM, M=25, N=128, K=64; 2 m-tiles sequential ----
#pragma unroll
  for (int mt = 0; mt < 2; ++mt) {
    int row = mt * 16 + l15;
    int pos = row < 24 ? row : 24;
    int ii = pos / 5, jj = pos - ii * 5;
    const __bf16* xp = xs + ii * 6 + jj;
    bf16x8 af[2];
#pragma unroll
    for (int ks = 0; ks < 2; ++ks) {
      const __bf16* p0 = xp + (ks * 8 + quad * 2) * 36;
      bf16x8 a;
      a[0] = p0[0];  a[1] = p0[1];  a[2] = p0[6];  a[3] = p0[7];
      a[4] = p0[36]; a[5] = p0[37]; a[6] = p0[42]; a[7] = p0[43];
      af[ks] = a;
    }
    f32x4 acc[8];
#pragma unroll
    for (int nt = 0; nt < 8; ++nt) acc[nt] = (f32x4){0.f, 0.f, 0.f, 0.f};
#pragma unroll
    for (int ks = 0; ks < 2; ++ks)
#pragma unroll
      for (int nt = 0; nt < 8; ++nt)
        acc[nt] = mfma16(af[ks], bfr[nt][ks], acc[nt]);

#pragma unroll
    for (int r = 0; r < 4; ++r) {
      int orow = mt * 16 + quad * 4 + r;
      if (orow < 25) {
#pragma unroll
        for (int nt = 0; nt < 8; ++nt) {
          float v = acc[nt][r] + bias[nt];
          if (nt < 2) {  // conv_out ch 0..31 -> global with relu
            act[((size_t)b * 25 + orow) * 64 + nt * 16 + l15] =
                __float2bfloat16(fmaxf(v, 0.f));
          } else {       // qkv ch 0..95 -> LDS (k already log2e-scaled via weights)
            qs[((nt - 2) * 16 + l15) * 28 + orow] = __float2bfloat16(v);
          }
        }
      }
    }
  }

  // ---- phase 2: attention, dkh=1; e = 2^(q * k*log2e) via raw v_exp_f32;
  //      5 independent acc chains; lane n=t&31 owns head n, half=t>>5 splits i. ----
  {
    const int n = t & 31, half = t >> 5;
    const __bf16* qp = qs + n * 28;
    const __bf16* kp = qs + (32 + n) * 28;
    const __bf16* vp = qs + (64 + n) * 28;
    float kl[25], vv[25];
#pragma unroll
    for (int c4 = 0; c4 < 6; ++c4) {
      bf16x4 bb = *(const bf16x4*)(kp + c4 * 4);
      bf16x4 cc = *(const bf16x4*)(vp + c4 * 4);
#pragma unroll
      for (int z = 0; z < 4; ++z) {
        kl[c4 * 4 + z] = (float)bb[z];
        vv[c4 * 4 + z] = (float)cc[z];
      }
    }
    kl[24] = (float)kp[24]; vv[24] = (float)vp[24];

    const int i0 = half * 12;
    float qv[13];
    {
      const __bf16* qbase = qp + i0;  // row*56 + i0*2: 8B-aligned for i0 in {0,12}
      bf16x4 q0 = *(const bf16x4*)(qbase);
      bf16x4 q1 = *(const bf16x4*)(qbase + 4);
      bf16x4 q2 = *(const bf16x4*)(qbase + 8);
#pragma unroll
      for (int z = 0; z < 4; ++z) {
        qv[z] = (float)q0[z]; qv[4 + z] = (float)q1[z]; qv[8 + z] = (float)q2[z];
      }
      qv[12] = (float)qbase[12];
    }

#pragma unroll
    for (int z = 0; z < 13; ++z) {
      const float qi = qv[z];
      float s0 = 0.f, s1 = 0.f, s2 = 0.f, s3 = 0.f, s4 = 0.f;
      float o0 = 0.f, o1 = 0.f, o2 = 0.f, o3 = 0.f, o4 = 0.f;
#pragma unroll
      for (int g = 0; g < 5; ++g) {
        float e0 = fast_exp2(qi * kl[g * 5 + 0]);
        float e1 = fast_exp2(qi * kl[g * 5 + 1]);
        float e2 = fast_exp2(qi * kl[g * 5 + 2]);
        float e3 = fast_exp2(qi * kl[g * 5 + 3]);
        float e4 = fast_exp2(qi * kl[g * 5 + 4]);
        s0 += e0; o0 = __builtin_fmaf(e0, vv[g * 5 + 0], o0);
        s1 += e1; o1 = __builtin_fmaf(e1, vv[g * 5 + 1], o1);
        s2 += e2; o2 = __builtin_fmaf(e2, vv[g * 5 + 2], o2);
        s3 += e3; o3 = __builtin_fmaf(e3, vv[g * 5 + 3], o3);
        s4 += e4; o4 = __builtin_fmaf(e4, vv[g * 5 + 4], o4);
      }
      float ss = ((s0 + s1) + (s2 + s3)) + s4;
      float oo = ((o0 + o1) + (o2 + o3)) + o4;
      as_[(i0 + z) * 32 + n] = __float2bfloat16(oo * __builtin_amdgcn_rcpf(ss));
    }
  }

  // ---- phase 3: 1x1 conv via MFMA. M=25 rows, K=32 heads, N=32 ----
  {
    bf16x8 bw[2]; float ab[2];
#pragma unroll
    for (int nt2 = 0; nt2 < 2; ++nt2) {
      int n = nt2 * 16 + l15;
      bw[nt2] = *(const bf16x8*)((const __bf16*)wab + n * 32 + quad * 8);
      ab[nt2] = attn_b[n];
    }
#pragma unroll
    for (int mt = 0; mt < 2; ++mt) {
      int row = mt * 16 + l15;
      int rc = row < 24 ? row : 24;
      bf16x8 af = *(const bf16x8*)(as_ + rc * 32 + quad * 8);
      f32x4 acc[2];
#pragma unroll
      for (int nt2 = 0; nt2 < 2; ++nt2)
        acc[nt2] = mfma16(af, bw[nt2], (f32x4){0.f, 0.f, 0.f, 0.f});
#pragma unroll
      for (int r = 0; r < 4; ++r) {
        int orow = mt * 16 + quad * 4 + r;
        if (orow < 25) {
#pragma unroll
          for (int nt2 = 0; nt2 < 2; ++nt2)
            act[((size_t)b * 25 + orow) * 64 + 32 + nt2 * 16 + l15] =
                __float2bfloat16(fmaxf(acc[nt2][r] + ab[nt2], 0.f));
        }
      }
    }
  }
}

// ---------------- k2: fused dense chain — R2-proven 32-row/2-acc shape (unchanged) ----------------
__global__ __launch_bounds__(512) void k2(
    const __hip_bfloat16* __restrict__ act,
    const __hip_bfloat16* __restrict__ w1bp, const float* __restrict__ b1,
    const __hip_bfloat16* __restrict__ w2b, const float* __restrict__ b2,
    const float* __restrict__ w3, const float* __restrict__ b3,
    float* __restrict__ out) {
  const int t = threadIdx.x;
  const int lane = t & 63;
  const int wave = t >> 6;   // 0..7
  const int wm = wave >> 2;  // 0..1
  const int wn = wave & 3;   // 0..3
  const int l15 = lane & 15;
  const int quad = lane >> 4;  // 0..3
  const int b0 = blockIdx.x * 32;

  __shared__ __hip_bfloat16 C1s[32 * 136];
  __shared__ __hip_bfloat16 C2s[32 * 72];

  // ---- layer 1: [32,1600] x [128,1600]^T ----
  f32x4 acc0 = {0.f, 0.f, 0.f, 0.f};
  f32x4 acc1 = {0.f, 0.f, 0.f, 0.f};
  const __bf16* aptr  = (const __bf16*)act + (size_t)(b0 + wm * 16 + l15) * 1600 + quad * 8;
  const __bf16* bptr0 = (const __bf16*)w1bp + (size_t)(wn * 32 + l15) * 1600 + quad * 8;
  const __bf16* bptr1 = bptr0 + 16 * 1600;
#pragma unroll 5
  for (int k0 = 0; k0 < 1600; k0 += 32) {
    bf16x8 av  = *(const bf16x8*)(aptr + k0);
    bf16x8 bv0 = *(const bf16x8*)(bptr0 + k0);
    bf16x8 bv1 = *(const bf16x8*)(bptr1 + k0);
    acc0 = mfma16(av, bv0, acc0);
    acc1 = mfma16(av, bv1, acc1);
  }
  {
    const int col0 = wn * 32 + l15;
    const float bias0 = b1[col0];
    const float bias1 = b1[col0 + 16];
#pragma unroll
    for (int r = 0; r < 4; ++r) {
      const int row = wm * 16 + quad * 4 + r;
      C1s[row * 136 + col0]      = __float2bfloat16(fmaxf(acc0[r] + bias0, 0.f));
      C1s[row * 136 + col0 + 16] = __float2bfloat16(fmaxf(acc1[r] + bias1, 0.f));
    }
  }
  __syncthreads();

  // ---- layer 2: [32,128] x [64,128]^T ----
  f32x4 acc2 = {0.f, 0.f, 0.f, 0.f};
  {
    const __bf16* aL = (const __bf16*)C1s + (wm * 16 + l15) * 136 + quad * 8;
    const __bf16* bL = (const __bf16*)w2b + (wn * 16 + l15) * 128 + quad * 8;
#pragma unroll
    for (int k0 = 0; k0 < 128; k0 += 32)
      acc2 = mfma16(*(const bf16x8*)(aL + k0), *(const bf16x8*)(bL + k0), acc2);
  }
  {
    const int col = wn * 16 + l15;
    const float bias = b2[col];
#pragma unroll
    for (int r = 0; r < 4; ++r) {
      const int row = wm * 16 + quad * 4 + r;
      C2s[row * 72 + col] = __float2bfloat16(fmaxf(acc2[r] + bias, 0.f));
    }
  }
  __syncthreads();

  // ---- layer 3 (scalar, 160 outputs) ----
  if (t < 160) {
    const int row = t / 5;
    const int oc = t - row * 5;
    float s = b3[oc];
#pragma unroll
    for (int k = 0; k < 64; ++k)
      s += __bfloat162float(C2s[row * 72 + k]) * w3[oc * 64 + k];
    out[(size_t)(b0 + row) * 5 + oc] = s;
  }
}

extern "C" void kernel_launch(void* const* d_in, const int* in_sizes, int n_in,
                              void* d_out, int out_size, void* d_ws, size_t ws_size,
                              hipStream_t stream) {
  const float* x      = (const float*)d_in[0];
  const float* conv_w = (const float*)d_in[1];
  const float* conv_b = (const float*)d_in[2];
  const float* qkv_w  = (const float*)d_in[3];
  const float* qkv_b  = (const float*)d_in[4];
  const float* attn_w = (const float*)d_in[5];
  const float* attn_b = (const float*)d_in[6];
  const float* w1 = (const float*)d_in[7];
  const float* b1 = (const float*)d_in[8];
  const float* w2 = (const float*)d_in[9];
  const float* b2 = (const float*)d_in[10];
  const float* w3 = (const float*)d_in[11];
  const float* b3 = (const float*)d_in[12];
  float* out = (float*)d_out;

  // workspace layout (16B-aligned):
  //   act   [8192][25][64] bf16 : 26,214,400 B
  //   w1bp  [128][1600]    bf16 :    409,600 B  (written by k1 tail units 0..127)
  //   w2b   [64][128]      bf16 :     16,384 B  (written by k1 tail units 128..131)
  //   wqb   [128][64]      bf16 :     16,384 B  (k rows pre-scaled by log2e)
  //   biasb [128]          f32  :        512 B  (k entries pre-scaled by log2e)
  //   wab   [32][32]       bf16 :      2,048 B
  char* ws = (char*)d_ws;
  __hip_bfloat16* act   = (__hip_bfloat16*)ws;
  __hip_bfloat16* w1bp  = (__hip_bfloat16*)(ws + 26214400);
  __hip_bfloat16* w2b   = (__hip_bfloat16*)(ws + 26624000);
  __hip_bfloat16* wqb   = (__hip_bfloat16*)(ws + 26640384);
  float*          biasb = (float*)(ws + 26656768);
  __hip_bfloat16* wab   = (__hip_bfloat16*)(ws + 26657280);

  prep_small<<<dim3(17), dim3(64), 0, stream>>>(conv_w, conv_b, qkv_w, qkv_b, attn_w,
                                                wqb, biasb, wab);
  k1<<<dim3(2048 + 33), dim3(256), 0, stream>>>(x, biasb, wqb, wab, attn_b,
                                                w1, w2, act, w1bp, w2b);
  k2<<<dim3(256), dim3(512), 0, stream>>>(act, w1bp, b1, w2b, b2, w3, b3, out);
}

// Round 14
// 158.820 us; speedup vs baseline: 1.3517x; 1.0406x over previous
//
#include <hip/hip_runtime.h>
#include <hip/hip_bf16.h>
#include <cstdint>
#include <cstddef>

// B=8192, CIN=16, 6x6->5x5 (k=2 VALID), FM=64, DK=DV=NH=32 (dkh=1), HID=128, OUT=5.
// R14 = R12 (best k1: 2 waves/block, private LDS, zero barriers) with phase-2
// inner loop in PACKED fp32 (v_pk_mul/add/fma_f32, full-rate on CDNA4): pairs of
// j per packed op, exp scalar. 30% issue-cycle cut on the dominant loop.
// act layout [b][pos][ch] (dense K-permuted); w1bp pre-permuted to match.

typedef __attribute__((ext_vector_type(4))) float f32x4;
typedef __attribute__((ext_vector_type(2))) float f32x2;
typedef __attribute__((ext_vector_type(8))) __bf16 bf16x8;
typedef __attribute__((ext_vector_type(4))) __bf16 bf16x4;

#define LOG2E 1.4426950408889634f

// raw v_exp_f32 (2^x) — exp2f() lowers to the OCML wrapper (~4 extra VALU ops),
// measured as the R4->R6 attention regression (R7 confirmed the fix: -20us).
__device__ __forceinline__ float fast_exp2(float x) {
#if __has_builtin(__builtin_amdgcn_exp2f)
  return __builtin_amdgcn_exp2f(x);
#else
  return __expf(x * 0.6931471805599453f);
#endif
}

// v_mfma_f32_16x16x32_bf16 (bench-verified layout R2-R13):
// A: lane holds A[m=lane&15][k=quad*8+j]; B: W[n=lane&15][k=quad*8+j];
// C/D: col=lane&15, row=quad*4+reg.
__device__ __forceinline__ f32x4 mfma16(bf16x8 a, bf16x8 b, f32x4 c) {
  return __builtin_amdgcn_mfma_f32_16x16x32_bf16(a, b, c, 0, 0, 0);
}

// ---------------- prep_small: ONLY what k1's main blocks read (unchanged) ----------------
__global__ __launch_bounds__(64) void prep_small(
    const float* __restrict__ conv_w, const float* __restrict__ conv_b,
    const float* __restrict__ qkv_w,  const float* __restrict__ qkv_b,
    const float* __restrict__ attn_w,
    __hip_bfloat16* __restrict__ wqb, float* __restrict__ biasb,
    __hip_bfloat16* __restrict__ wab) {
  const int t = threadIdx.x, tb = blockIdx.x;
  if (tb < 16) {
#pragma unroll
    for (int j = 0; j < 8; ++j) {
      int i = tb * 512 + j * 64 + t;
      float w = (i < 2048) ? conv_w[i] : qkv_w[i - 2048];
      if (i >= 4096 && i < 6144) w *= LOG2E;  // k-channel rows 64..95
      wqb[i] = __float2bfloat16(w);
    }
  } else {
#pragma unroll
    for (int j = 0; j < 16; ++j) wab[j * 64 + t] = __float2bfloat16(attn_w[j * 64 + t]);
    for (int i = t; i < 128; i += 64) {
      float b = (i < 32) ? conv_b[i] : qkv_b[i - 32];
      if (i >= 64 && i < 96) b *= LOG2E;
      biasb[i] = b;
    }
  }
}

// ---------------- k1: fused conv+qkv GEMM + attention + 1x1 conv ----------------
// Main blocks 0..4095: 2 waves x 1 batch each, private LDS region, no barriers.
// Tail blocks 4096..4161: 2 waves x 1 prep unit each (w1bp rows / w2b cast).
__global__ __launch_bounds__(128) void k1(
    const float* __restrict__ x,
    const float* __restrict__ biasb,
    const __hip_bfloat16* __restrict__ wqb,
    const __hip_bfloat16* __restrict__ wab, const float* __restrict__ attn_b,
    const float* __restrict__ w1, const float* __restrict__ w2,
    __hip_bfloat16* __restrict__ act,
    __hip_bfloat16* __restrict__ w1bp, __hip_bfloat16* __restrict__ w2b) {
  const int t = threadIdx.x & 63;   // lane within wave
  const int wv = threadIdx.x >> 6;  // wave 0/1 in block

  __shared__ __align__(16) char lds_raw[2 * 7168];
  char* my = lds_raw + wv * 7168;   // private per-wave region

  // ---- tail blocks: k2-input prep (runs in main-grid drain shadow) ----
  if (blockIdx.x >= 4096) {
    const int u = (blockIdx.x - 4096) * 2 + wv;  // unit 0..131
    if (u < 128) {
      // w1bp row u: coalesced fp32 read -> LDS -> coalesced permuted bf16 write.
      float* rowf = (float*)my;  // 6400 B <= 7168 OK
      const float* wr = w1 + u * 1600;
#pragma unroll
      for (int j = 0; j < 25; ++j) rowf[j * 64 + t] = wr[j * 64 + t];
      // single wave: same-wave LDS RAW ordered by lgkmcnt (no barrier needed)
      __hip_bfloat16* wo = w1bp + u * 1600;
#pragma unroll
      for (int j = 0; j < 25; ++j) {
        // read lds[t*25+j]: stride-25 dwords, gcd(25,32)=1 -> conflict-free
        wo[j * 64 + t] = __float2bfloat16(rowf[t * 25 + j]);
      }
    } else if (u < 132) {  // w2b cast (2048 each, coalesced)
#pragma unroll
      for (int j = 0; j < 32; ++j) {
        int i = (u - 128) * 2048 + j * 64 + t;
        w2b[i] = __float2bfloat16(w2[i]);
      }
    }
    return;
  }

  // ================= main path =================
  const int l15 = t & 15, quad = t >> 4;
  const int b = blockIdx.x * 2 + wv;
  __bf16* xs  = (__bf16*)my;          // phase 1 (576 elems)
  __bf16* as_ = (__bf16*)my;          // phase 2/3 (800 elems, stride 32)
  __bf16* qs  = (__bf16*)(my + 1600); // q:0-31 k:32-63(x log2e) v:64-95, stride 28

  // ---- stage x -> bf16 LDS (576 floats, coalesced; same-wave ordering) ----
  const float* xb = x + (size_t)b * 576;
#pragma unroll
  for (int i = 0; i < 9; ++i) {
    int f = t + i * 64;
    xs[f] = __float2bfloat16(xb[f]);
  }

  // ---- B-frags from bf16 wqb (L2-hot 16KB) + pre-scaled biases ----
  bf16x8 bfr[8][2];
#pragma unroll
  for (int nt = 0; nt < 8; ++nt)
#pragma unroll
    for (int ks = 0; ks < 2; ++ks)
      bfr[nt][ks] = *(const bf16x8*)((const __bf16*)wqb + (nt * 16 + l15) * 64 + ks * 32 + quad * 8);
  float bias[8];
#pragma unroll
  for (int nt = 0; nt < 8; ++nt) bias[nt] = biasb[nt * 16 + l15];

  // ---- phase 1: implicit GEMM, M=25, N=128, K=64; 2 m-tiles sequential ----
#pragma unroll
  for (int mt = 0; mt < 2; ++mt) {
    int row = mt * 16 + l15;
    int pos = row < 24 ? row : 24;
    int ii = pos / 5, jj = pos - ii * 5;
    const __bf16* xp = xs + ii * 6 + jj;
    bf16x8 af[2];
#pragma unroll
    for (int ks = 0; ks < 2; ++ks) {
      const __bf16* p0 = xp + (ks * 8 + quad * 2) * 36;
      bf16x8 a;
      a[0] = p0[0];  a[1] = p0[1];  a[2] = p0[6];  a[3] = p0[7];
      a[4] = p0[36]; a[5] = p0[37]; a[6] = p0[42]; a[7] = p0[43];
      af[ks] = a;
    }
    f32x4 acc[8];
#pragma unroll
    for (int nt = 0; nt < 8; ++nt) acc[nt] = (f32x4){0.f, 0.f, 0.f, 0.f};
#pragma unroll
    for (int ks = 0; ks < 2; ++ks)
#pragma unroll
      for (int nt = 0; nt < 8; ++nt)
        acc[nt] = mfma16(af[ks], bfr[nt][ks], acc[nt]);

#pragma unroll
    for (int r = 0; r < 4; ++r) {
      int orow = mt * 16 + quad * 4 + r;
      if (orow < 25) {
#pragma unroll
        for (int nt = 0; nt < 8; ++nt) {
          float v = acc[nt][r] + bias[nt];
          if (nt < 2) {  // conv_out ch 0..31 -> global with relu
            act[((size_t)b * 25 + orow) * 64 + nt * 16 + l15] =
                __float2bfloat16(fmaxf(v, 0.f));
          } else {       // qkv ch 0..95 -> LDS (k already log2e-scaled via weights)
            qs[((nt - 2) * 16 + l15) * 28 + orow] = __float2bfloat16(v);
          }
        }
      }
    }
  }

  // ---- phase 2: attention, dkh=1; e = 2^(q * k*log2e) via raw v_exp_f32.
  //      PACKED inner loop: j in pairs via v_pk_mul/add/fma_f32 (full-rate fp32
  //      pairs on CDNA4); 4 packed + 1 scalar acc chains. ----
  {
    const int n = t & 31, half = t >> 5;
    const __bf16* qp = qs + n * 28;
    const __bf16* kp = qs + (32 + n) * 28;
    const __bf16* vp = qs + (64 + n) * 28;
    f32x2 kl2[12], vv2[12];
    float kl24, vv24;
#pragma unroll
    for (int c4 = 0; c4 < 6; ++c4) {
      bf16x4 bb = *(const bf16x4*)(kp + c4 * 4);
      bf16x4 cc = *(const bf16x4*)(vp + c4 * 4);
      kl2[c4 * 2]     = (f32x2){(float)bb[0], (float)bb[1]};
      kl2[c4 * 2 + 1] = (f32x2){(float)bb[2], (float)bb[3]};
      vv2[c4 * 2]     = (f32x2){(float)cc[0], (float)cc[1]};
      vv2[c4 * 2 + 1] = (f32x2){(float)cc[2], (float)cc[3]};
    }
    kl24 = (float)kp[24]; vv24 = (float)vp[24];

    const int i0 = half * 12;
    float qv[13];
    {
      const __bf16* qbase = qp + i0;  // row*56 + i0*2: 8B-aligned for i0 in {0,12}
      bf16x4 q0 = *(const bf16x4*)(qbase);
      bf16x4 q1 = *(const bf16x4*)(qbase + 4);
      bf16x4 q2 = *(const bf16x4*)(qbase + 8);
#pragma unroll
      for (int z = 0; z < 4; ++z) {
        qv[z] = (float)q0[z]; qv[4 + z] = (float)q1[z]; qv[8 + z] = (float)q2[z];
      }
      qv[12] = (float)qbase[12];
    }

#pragma unroll
    for (int z = 0; z < 13; ++z) {
      const float qi = qv[z];
      const f32x2 qi2 = {qi, qi};
      f32x2 sA = {0.f, 0.f}, sB = {0.f, 0.f};
      f32x2 oA = {0.f, 0.f}, oB = {0.f, 0.f};
      float s4 = 0.f, o4 = 0.f;
#pragma unroll
      for (int p = 0; p < 6; ++p) {
        f32x2 mA = qi2 * kl2[p];          // v_pk_mul_f32
        f32x2 mB = qi2 * kl2[p + 6];
        f32x2 eA = {fast_exp2(mA.x), fast_exp2(mA.y)};
        f32x2 eB = {fast_exp2(mB.x), fast_exp2(mB.y)};
        sA += eA;                          // v_pk_add_f32
        sB += eB;
        oA = eA * vv2[p] + oA;             // v_pk_fma_f32 (fp-contract)
        oB = eB * vv2[p + 6] + oB;
      }
      {
        float e = fast_exp2(qi * kl24);
        s4 += e;
        o4 = __builtin_fmaf(e, vv24, o4);
      }
      float ss = ((sA.x + sA.y) + (sB.x + sB.y)) + s4;
      float oo = ((oA.x + oA.y) + (oB.x + oB.y)) + o4;
      as_[(i0 + z) * 32 + n] = __float2bfloat16(oo * __builtin_amdgcn_rcpf(ss));
    }
  }

  // ---- phase 3: 1x1 conv via MFMA. M=25 rows, K=32 heads, N=32 ----
  {
    bf16x8 bw[2]; float ab[2];
#pragma unroll
    for (int nt2 = 0; nt2 < 2; ++nt2) {
      int n = nt2 * 16 + l15;
      bw[nt2] = *(const bf16x8*)((const __bf16*)wab + n * 32 + quad * 8);
      ab[nt2] = attn_b[n];
    }
#pragma unroll
    for (int mt = 0; mt < 2; ++mt) {
      int row = mt * 16 + l15;
      int rc = row < 24 ? row : 24;
      bf16x8 af = *(const bf16x8*)(as_ + rc * 32 + quad * 8);
      f32x4 acc[2];
#pragma unroll
      for (int nt2 = 0; nt2 < 2; ++nt2)
        acc[nt2] = mfma16(af, bw[nt2], (f32x4){0.f, 0.f, 0.f, 0.f});
#pragma unroll
      for (int r = 0; r < 4; ++r) {
        int orow = mt * 16 + quad * 4 + r;
        if (orow < 25) {
#pragma unroll
          for (int nt2 = 0; nt2 < 2; ++nt2)
            act[((size_t)b * 25 + orow) * 64 + 32 + nt2 * 16 + l15] =
                __float2bfloat16(fmaxf(acc[nt2][r] + ab[nt2], 0.f));
        }
      }
    }
  }
}

// ---------------- k2: fused dense chain — R2-proven 32-row/2-acc shape (unchanged) ----------------
__global__ __launch_bounds__(512) void k2(
    const __hip_bfloat16* __restrict__ act,
    const __hip_bfloat16* __restrict__ w1bp, const float* __restrict__ b1,
    const __hip_bfloat16* __restrict__ w2b, const float* __restrict__ b2,
    const float* __restrict__ w3, const float* __restrict__ b3,
    float* __restrict__ out) {
  const int t = threadIdx.x;
  const int lane = t & 63;
  const int wave = t >> 6;   // 0..7
  const int wm = wave >> 2;  // 0..1
  const int wn = wave & 3;   // 0..3
  const int l15 = lane & 15;
  const int quad = lane >> 4;  // 0..3
  const int b0 = blockIdx.x * 32;

  __shared__ __hip_bfloat16 C1s[32 * 136];
  __shared__ __hip_bfloat16 C2s[32 * 72];

  // ---- layer 1: [32,1600] x [128,1600]^T ----
  f32x4 acc0 = {0.f, 0.f, 0.f, 0.f};
  f32x4 acc1 = {0.f, 0.f, 0.f, 0.f};
  const __bf16* aptr  = (const __bf16*)act + (size_t)(b0 + wm * 16 + l15) * 1600 + quad * 8;
  const __bf16* bptr0 = (const __bf16*)w1bp + (size_t)(wn * 32 + l15) * 1600 + quad * 8;
  const __bf16* bptr1 = bptr0 + 16 * 1600;
#pragma unroll 5
  for (int k0 = 0; k0 < 1600; k0 += 32) {
    bf16x8 av  = *(const bf16x8*)(aptr + k0);
    bf16x8 bv0 = *(const bf16x8*)(bptr0 + k0);
    bf16x8 bv1 = *(const bf16x8*)(bptr1 + k0);
    acc0 = mfma16(av, bv0, acc0);
    acc1 = mfma16(av, bv1, acc1);
  }
  {
    const int col0 = wn * 32 + l15;
    const float bias0 = b1[col0];
    const float bias1 = b1[col0 + 16];
#pragma unroll
    for (int r = 0; r < 4; ++r) {
      const int row = wm * 16 + quad * 4 + r;
      C1s[row * 136 + col0]      = __float2bfloat16(fmaxf(acc0[r] + bias0, 0.f));
      C1s[row * 136 + col0 + 16] = __float2bfloat16(fmaxf(acc1[r] + bias1, 0.f));
    }
  }
  __syncthreads();

  // ---- layer 2: [32,128] x [64,128]^T ----
  f32x4 acc2 = {0.f, 0.f, 0.f, 0.f};
  {
    const __bf16* aL = (const __bf16*)C1s + (wm * 16 + l15) * 136 + quad * 8;
    const __bf16* bL = (const __bf16*)w2b + (wn * 16 + l15) * 128 + quad * 8;
#pragma unroll
    for (int k0 = 0; k0 < 128; k0 += 32)
      acc2 = mfma16(*(const bf16x8*)(aL + k0), *(const bf16x8*)(bL + k0), acc2);
  }
  {
    const int col = wn * 16 + l15;
    const float bias = b2[col];
#pragma unroll
    for (int r = 0; r < 4; ++r) {
      const int row = wm * 16 + quad * 4 + r;
      C2s[row * 72 + col] = __float2bfloat16(fmaxf(acc2[r] + bias, 0.f));
    }
  }
  __syncthreads();

  // ---- layer 3 (scalar, 160 outputs) ----
  if (t < 160) {
    const int row = t / 5;
    const int oc = t - row * 5;
    float s = b3[oc];
#pragma unroll
    for (int k = 0; k < 64; ++k)
      s += __bfloat162float(C2s[row * 72 + k]) * w3[oc * 64 + k];
    out[(size_t)(b0 + row) * 5 + oc] = s;
  }
}

extern "C" void kernel_launch(void* const* d_in, const int* in_sizes, int n_in,
                              void* d_out, int out_size, void* d_ws, size_t ws_size,
                              hipStream_t stream) {
  const float* x      = (const float*)d_in[0];
  const float* conv_w = (const float*)d_in[1];
  const float* conv_b = (const float*)d_in[2];
  const float* qkv_w  = (const float*)d_in[3];
  const float* qkv_b  = (const float*)d_in[4];
  const float* attn_w = (const float*)d_in[5];
  const float* attn_b = (const float*)d_in[6];
  const float* w1 = (const float*)d_in[7];
  const float* b1 = (const float*)d_in[8];
  const float* w2 = (const float*)d_in[9];
  const float* b2 = (const float*)d_in[10];
  const float* w3 = (const float*)d_in[11];
  const float* b3 = (const float*)d_in[12];
  float* out = (float*)d_out;

  // workspace layout (16B-aligned):
  //   act   [8192][25][64] bf16 : 26,214,400 B
  //   w1bp  [128][1600]    bf16 :    409,600 B  (written by k1 tail units 0..127)
  //   w2b   [64][128]      bf16 :     16,384 B  (written by k1 tail units 128..131)
  //   wqb   [128][64]      bf16 :     16,384 B  (k rows pre-scaled by log2e)
  //   biasb [128]          f32  :        512 B  (k entries pre-scaled by log2e)
  //   wab   [32][32]       bf16 :      2,048 B
  char* ws = (char*)d_ws;
  __hip_bfloat16* act   = (__hip_bfloat16*)ws;
  __hip_bfloat16* w1bp  = (__hip_bfloat16*)(ws + 26214400);
  __hip_bfloat16* w2b   = (__hip_bfloat16*)(ws + 26624000);
  __hip_bfloat16* wqb   = (__hip_bfloat16*)(ws + 26640384);
  float*          biasb = (float*)(ws + 26656768);
  __hip_bfloat16* wab   = (__hip_bfloat16*)(ws + 26657280);

  prep_small<<<dim3(17), dim3(64), 0, stream>>>(conv_w, conv_b, qkv_w, qkv_b, attn_w,
                                                wqb, biasb, wab);
  k1<<<dim3(4096 + 66), dim3(128), 0, stream>>>(x, biasb, wqb, wab, attn_b,
                                                w1, w2, act, w1bp, w2b);
  k2<<<dim3(256), dim3(512), 0, stream>>>(act, w1bp, b1, w2b, b2, w3, b3, out);
}